// Round 7
// baseline (256.447 us; speedup 1.0000x reference)
//
#include <hip/hip_runtime.h>

typedef unsigned short u16;
typedef unsigned int u32;
typedef __attribute__((ext_vector_type(8))) short bf16x8;   // 8 bf16 in 4 VGPRs
typedef __attribute__((ext_vector_type(4))) float f32x4;

// ---------- bf16 helpers (RNE) ----------
__device__ __forceinline__ u16 f2bf(float f) {
  union { float f; u32 u; } v; v.f = f;
  u32 u = v.u;
  return (u16)((u + 0x7FFFu + ((u >> 16) & 1u)) >> 16);
}
__device__ __forceinline__ float bf2f(u16 s) {
  union { u32 u; float f; } v; v.u = ((u32)s) << 16;
  return v.f;
}

// ---------- async global->LDS (16B per lane) ----------
__device__ __forceinline__ void async16(const void* g, void* l) {
  __builtin_amdgcn_global_load_lds(
      (__attribute__((address_space(1))) void*)g,
      (__attribute__((address_space(3))) void*)l, 16, 0, 0);
}

// ---------- prep1: fused {4x weight transpose+cast, x cast, trig table} ----------
__global__ void prep1_kernel(const float* __restrict__ x,
                             const float* __restrict__ W0, const float* __restrict__ W1,
                             const float* __restrict__ W2, const float* __restrict__ W3,
                             const float* __restrict__ freqs,
                             u16* __restrict__ xbf, u16* __restrict__ wqkvT,
                             u16* __restrict__ woT,
                             float* __restrict__ ct, float* __restrict__ st) {
  __shared__ float tile[32][33];
  const int bid = blockIdx.x;
  const int tid = threadIdx.x;
  if (bid < 16384) {
    const int z = bid >> 12;
    const float* in = z == 0 ? W0 : z == 1 ? W1 : z == 2 ? W2 : W3;
    u16* out = z == 3 ? woT : wqkvT + (size_t)z * 4194304;
    const int local = bid & 4095;
    const int c0 = (local & 63) * 32, r0 = (local >> 6) * 32;
    const int tx = tid & 31, ty = tid >> 5;
#pragma unroll
    for (int i = ty; i < 32; i += 8) tile[i][tx] = in[(size_t)(r0 + i) * 2048 + c0 + tx];
    __syncthreads();
#pragma unroll
    for (int i = ty; i < 32; i += 8)
      out[(size_t)(c0 + i) * 2048 + r0 + tx] = f2bf(tile[tx][i]);
  } else if (bid < 24576) {
    int i = (bid - 16384) * 256 + tid;     // < 2097152
    float4 v = ((const float4*)x)[i];
    ushort4 o;
    o.x = f2bf(v.x); o.y = f2bf(v.y); o.z = f2bf(v.z); o.w = f2bf(v.w);
    ((ushort4*)xbf)[i] = o;
  } else {
    int i = (bid - 24576) * 256 + tid;     // < 262144
    float f = freqs[i];
    ct[i] = cosf(f); st[i] = sinf(f);
  }
}

// ---------- prep2: fused {k RoPE -> Kp [h][s][128], V repack -> VT2} ----------
// q is NOT rotated here; attn applies q-RoPE on load.
__global__ void prep2_kernel(const u16* __restrict__ k, u16* __restrict__ Kp,
                             const u16* __restrict__ Vin, u16* __restrict__ VT2,
                             const float* __restrict__ ct, const float* __restrict__ st) {
  __shared__ u16 lv[64][132];
  const int bid = blockIdx.x;
  const int tid = threadIdx.x;
  if (bid < 8192) {
    int i = bid * 256 + tid;                  // over S*H*32 = 2,097,152
    int dp = (i & 31) * 2;
    int hh = (i >> 5) & 15;
    int s  = i >> 9;
    float c0 = ct[s * 64 + dp], c1 = ct[s * 64 + dp + 1];
    float s0 = st[s * 64 + dp], s1 = st[s * 64 + dp + 1];
    size_t base = (size_t)s * 2048 + hh * 128 + dp;
    u32 lo = *(const u32*)(k + base);
    u32 hi = *(const u32*)(k + base + 64);
    float a0 = bf2f((u16)lo), a1 = bf2f((u16)(lo >> 16));
    float b0 = bf2f((u16)hi), b1 = bf2f((u16)(hi >> 16));
    u32 nlo = (u32)f2bf(a0 * c0 - b0 * s0) | ((u32)f2bf(a1 * c1 - b1 * s1) << 16);
    u32 nhi = (u32)f2bf(b0 * c0 + a0 * s0) | ((u32)f2bf(b1 * c1 + a1 * s1) << 16);
    size_t kpb = ((size_t)hh * 4096 + s) * 128 + dp;
    *(u32*)(Kp + kpb) = nlo;
    *(u32*)(Kp + kpb + 64) = nhi;
  } else {
    const int local = bid - 8192;             // 0..1023
    const int h = local >> 6;
    const int s0 = (local & 63) * 64;         // 4 tiles per block
#pragma unroll
    for (int i = 0; i < 16; ++i) {
      int idx = i * 256 + tid;
      int r = idx >> 6;
      int d2 = idx & 63;
      u32 vv = ((const u32*)Vin)[(size_t)(s0 + r) * 1024 + h * 64 + d2];
      *(u32*)(&lv[r][d2 * 2]) = vv;
    }
    __syncthreads();
#pragma unroll
    for (int i = 0; i < 16; ++i) {
      int idx = i * 256 + tid;               // 0..4095
      int k2 = idx & 7;                      // u32 over 2 keys
      int d  = (idx >> 3) & 127;
      int tl = idx >> 10;                    // local tile 0..3
      u32 lo = lv[tl * 16 + k2 * 2][d];
      u32 hi = lv[tl * 16 + k2 * 2 + 1][d];
      ((u32*)VT2)[(((size_t)h * 256 + (s0 >> 4) + tl) * 128 + d) * 8 + k2] = lo | (hi << 16);
    }
  }
}

// ---------- phased pipelined bf16 GEMM ----------
// BM=128, BN=256, BK=64, 512 thr (8 waves 2m x 4n, per-wave 64x64 C).
// 3-deep LDS K-tile pipeline (144 KB, 1 block/CU). Per K-tile: 2 sub-phases
// {ds_read subtile; issue 3 global_load_lds of tile t+2; barrier; lgkmcnt(0);
//  setprio(1); 16 MFMA; setprio(0); barrier}; one counted vmcnt(6) per K-tile
// (never 0 in steady state). Proven conflict-free XOR swizzle on 128B rows.
// Hazards: buf(t+2)=buf(t-1) writes are issued only after the barrier that
// closed tile t-1 (all its ds_reads lgkm0'd before that barrier); buf(t) reads
// follow the vmcnt+barrier pair that confirmed tile t's loads landed.
// MODE 0: f32 out. MODE 2: QKV-fused bf16 routing by 2048-col block.
template <int MODE>
__launch_bounds__(512, 1)
__global__ void gemm8p_kernel(const u16* __restrict__ A, const u16* __restrict__ Bt,
                              void* __restrict__ C, u16* __restrict__ D1, u16* __restrict__ D2,
                              int M, int N, int K) {
  __shared__ __align__(16) u16 As[3][128 * 64];   // 48 KB
  __shared__ __align__(16) u16 Bs[3][256 * 64];   // 96 KB
  const int tid = threadIdx.x;
  const int lane = tid & 63;
  const int wave = tid >> 6;
  const int wm = wave >> 2, wn = wave & 3;
  const int c = lane & 15, g = lane >> 4;
  const int brow = blockIdx.y * 128;
  const int bcol = blockIdx.x * 256;

  // staging offsets: linear LDS dest, inverse-swizzled global source
  int a_g[2], a_l[2], b_g[4], b_l[4];
#pragma unroll
  for (int i = 0; i < 2; ++i) {
    int p = i * 8192 + tid * 16;
    int row = p >> 7;
    int colb = (p & 127) ^ ((row & 7) << 4);
    a_g[i] = (brow + row) * K + (colb >> 1);
    a_l[i] = p;
  }
#pragma unroll
  for (int i = 0; i < 4; ++i) {
    int p = i * 8192 + tid * 16;
    int row = p >> 7;
    int colb = (p & 127) ^ ((row & 7) << 4);
    b_g[i] = (bcol + row) * K + (colb >> 1);
    b_l[i] = p;
  }

  f32x4 acc[4][4];
#pragma unroll
  for (int m = 0; m < 4; ++m)
#pragma unroll
    for (int n = 0; n < 4; ++n) acc[m][n] = (f32x4){0.f, 0.f, 0.f, 0.f};

  const int nt = K >> 6;
  // prologue: stage tiles 0,1; wait tile 0 (6 of 12 outstanding)
#pragma unroll
  for (int i = 0; i < 2; ++i) async16(A + a_g[i], (char*)As[0] + a_l[i]);
#pragma unroll
  for (int i = 0; i < 4; ++i) async16(Bt + b_g[i], (char*)Bs[0] + b_l[i]);
#pragma unroll
  for (int i = 0; i < 2; ++i) async16(A + a_g[i] + 64, (char*)As[1] + a_l[i]);
#pragma unroll
  for (int i = 0; i < 4; ++i) async16(Bt + b_g[i] + 64, (char*)Bs[1] + b_l[i]);
  asm volatile("s_waitcnt vmcnt(6)" ::: "memory");
  __builtin_amdgcn_sched_barrier(0);
  __builtin_amdgcn_s_barrier();

  int cur = 0;
  for (int t = 0; t < nt; ++t) {
    const int b = cur;
    int sb = cur + 2; if (sb >= 3) sb -= 3;
    const bool nb2 = (t + 2) < nt;
    const int k2 = (t + 2) << 6;
    const char* Ab = (const char*)As[b];
    const char* Bb = (const char*)Bs[b];

    bf16x8 af[2][4], b01[2][2], b23[2][2];
    // ---- phase 1: ds_read A(8) + B n=0,1 (4); stage A(2)+B(1) of t+2
#pragma unroll
    for (int m = 0; m < 4; ++m) {
      const int row = wm * 64 + m * 16 + c;
      const int rb = row << 7;
      const int sw = (row & 7) << 4;
#pragma unroll
      for (int ks = 0; ks < 2; ++ks)
        af[ks][m] = *(const bf16x8*)(Ab + rb + ((ks * 64 + (g << 4)) ^ sw));
    }
#pragma unroll
    for (int n = 0; n < 2; ++n) {
      const int row = wn * 64 + n * 16 + c;
      const int rb = row << 7;
      const int sw = (row & 7) << 4;
#pragma unroll
      for (int ks = 0; ks < 2; ++ks)
        b01[ks][n] = *(const bf16x8*)(Bb + rb + ((ks * 64 + (g << 4)) ^ sw));
    }
    if (nb2) {
      async16(A + a_g[0] + k2, (char*)As[sb] + a_l[0]);
      async16(A + a_g[1] + k2, (char*)As[sb] + a_l[1]);
      async16(Bt + b_g[0] + k2, (char*)Bs[sb] + b_l[0]);
    }
    __builtin_amdgcn_sched_barrier(0);
    __builtin_amdgcn_s_barrier();
    asm volatile("s_waitcnt lgkmcnt(0)" ::: "memory");
    __builtin_amdgcn_sched_barrier(0);
    __builtin_amdgcn_s_setprio(1);
#pragma unroll
    for (int ks = 0; ks < 2; ++ks)
#pragma unroll
      for (int m = 0; m < 4; ++m)
#pragma unroll
        for (int n = 0; n < 2; ++n)
          acc[m][n] = __builtin_amdgcn_mfma_f32_16x16x32_bf16(af[ks][m], b01[ks][n], acc[m][n], 0, 0, 0);
    __builtin_amdgcn_s_setprio(0);
    __builtin_amdgcn_sched_barrier(0);
    __builtin_amdgcn_s_barrier();

    // ---- phase 2: ds_read B n=2,3 (4); stage B(3) of t+2; counted vmcnt
#pragma unroll
    for (int n = 0; n < 2; ++n) {
      const int row = wn * 64 + (n + 2) * 16 + c;
      const int rb = row << 7;
      const int sw = (row & 7) << 4;
#pragma unroll
      for (int ks = 0; ks < 2; ++ks)
        b23[ks][n] = *(const bf16x8*)(Bb + rb + ((ks * 64 + (g << 4)) ^ sw));
    }
    if (nb2) {
      async16(Bt + b_g[1] + k2, (char*)Bs[sb] + b_l[1]);
      async16(Bt + b_g[2] + k2, (char*)Bs[sb] + b_l[2]);
      async16(Bt + b_g[3] + k2, (char*)Bs[sb] + b_l[3]);
      asm volatile("s_waitcnt vmcnt(6)" ::: "memory");   // t+1 landed, t+2 in flight
    } else if (t + 1 < nt) {
      asm volatile("s_waitcnt vmcnt(0)" ::: "memory");   // tail: drain last tile
    }
    __builtin_amdgcn_sched_barrier(0);
    __builtin_amdgcn_s_barrier();
    asm volatile("s_waitcnt lgkmcnt(0)" ::: "memory");
    __builtin_amdgcn_sched_barrier(0);
    __builtin_amdgcn_s_setprio(1);
#pragma unroll
    for (int ks = 0; ks < 2; ++ks)
#pragma unroll
      for (int m = 0; m < 4; ++m)
#pragma unroll
        for (int n = 0; n < 2; ++n)
          acc[m][n + 2] = __builtin_amdgcn_mfma_f32_16x16x32_bf16(af[ks][m], b23[ks][n], acc[m][n + 2], 0, 0, 0);
    __builtin_amdgcn_s_setprio(0);
    __builtin_amdgcn_sched_barrier(0);
    __builtin_amdgcn_s_barrier();

    cur += 1; if (cur == 3) cur = 0;
  }

  const int r0 = brow + wm * 64;
  if (MODE == 2) {
    const int sel = bcol >> 11;                       // block-uniform
    u16* dst = sel == 0 ? (u16*)C : sel == 1 ? D1 : D2;
    const int c0l = (bcol & 2047) + wn * 64;
#pragma unroll
    for (int m = 0; m < 4; ++m)
#pragma unroll
      for (int n = 0; n < 4; ++n)
#pragma unroll
        for (int r = 0; r < 4; ++r) {
          int rr = r0 + m * 16 + g * 4 + r;
          int cc = c0l + n * 16 + c;
          dst[(size_t)rr * 2048 + cc] = f2bf(acc[m][n][r]);
        }
  } else {
    const int c0 = bcol + wn * 64;
#pragma unroll
    for (int m = 0; m < 4; ++m)
#pragma unroll
      for (int n = 0; n < 4; ++n)
#pragma unroll
        for (int r = 0; r < 4; ++r) {
          int rr = r0 + m * 16 + g * 4 + r;
          int cc = c0 + n * 16 + c;
          ((float*)C)[(size_t)rr * N + cc] = acc[m][n][r];
        }
  }
}

// ---------- sparse tile attention: one block per (tile t, head h) ----------
// Q loaded un-rotated; q-RoPE applied in-register (pairs d<->d+64 are in the
// same thread's qr[ks]/qr[ks^2]). K from Kp [h][s][128]; V from VT2.
// bf16 softmax weights overlay the f32 logits buffer row-aligned.
__launch_bounds__(256, 6)
__global__ void attn_kernel(const u16* __restrict__ Q, const u16* __restrict__ Kp,
                            const u16* __restrict__ VT2, const int* __restrict__ anchors,
                            u16* __restrict__ Out,
                            const float* __restrict__ ct, const float* __restrict__ st) {
  const int t = blockIdx.x;   // 0..255
  const int h = blockIdx.y;   // 0..15
  __shared__ int tiles[20];
  __shared__ __align__(16) float lg[16][292];    // logits; weights overlay per-row
  const int tid  = threadIdx.x;
  const int lane = tid & 63;
  const int wave = tid >> 6;
  const int g = lane >> 4;          // k-group 0..3
  const int c = lane & 15;

  if (tid < 16) tiles[tid] = anchors[(size_t)((h << 12) + (t * 16 + 15)) * 16 + tid];
  if (tid == 16) tiles[16] = t;            // local tile (order: anchors then local)
  if (tid >= 17 && tid < 20) tiles[tid] = 0;   // dummy tiles (results discarded)
  __syncthreads();

  // ---- QK with fused q-RoPE; 5 fixed iters/wave, 1-ahead K prefetch
  {
    const int s = t * 16 + c;
    const u16* qbase = Q + (size_t)s * 2048 + h * 128 + g * 8;
    bf16x8 qr[4];
#pragma unroll
    for (int ks = 0; ks < 4; ++ks) qr[ks] = *(const bf16x8*)(qbase + ks * 32);
    // rope tables for dmod64 in [g*8,g*8+8) and [32+g*8,32+g*8+8)
    float c0[8], s0[8], c1[8], s1[8];
    const float* ctb = ct + s * 64;
    const float* stb = st + s * 64;
    *(float4*)&c0[0] = *(const float4*)(ctb + g * 8);
    *(float4*)&c0[4] = *(const float4*)(ctb + g * 8 + 4);
    *(float4*)&c1[0] = *(const float4*)(ctb + 32 + g * 8);
    *(float4*)&c1[4] = *(const float4*)(ctb + 32 + g * 8 + 4);
    *(float4*)&s0[0] = *(const float4*)(stb + g * 8);
    *(float4*)&s0[4] = *(const float4*)(stb + g * 8 + 4);
    *(float4*)&s1[0] = *(const float4*)(stb + 32 + g * 8);
    *(float4*)&s1[4] = *(const float4*)(stb + 32 + g * 8 + 4);
    bf16x8 qf[4];
#pragma unroll
    for (int j = 0; j < 8; ++j) {
      float f0 = bf2f((u16)qr[0][j]), f1 = bf2f((u16)qr[1][j]);
      float f2 = bf2f((u16)qr[2][j]), f3 = bf2f((u16)qr[3][j]);
      qf[0][j] = (short)f2bf(f0 * c0[j] - f2 * s0[j]);
      qf[1][j] = (short)f2bf(f1 * c1[j] - f3 * s1[j]);
      qf[2][j] = (short)f2bf(f2 * c0[j] + f0 * s0[j]);
      qf[3][j] = (short)f2bf(f3 * c1[j] + f1 * s1[j]);
    }

    int tok_[5];
    const u16* kb_[5];
#pragma unroll
    for (int i = 0; i < 5; ++i) {
      int j = wave + 4 * i;                  // < 20
      tok_[i] = tiles[j] * 16 + c;
      kb_[i] = Kp + ((size_t)h * 4096 + tok_[i]) * 128 + g * 8;
    }
    bf16x8 kfp[2][4];
#pragma unroll
    for (int ks = 0; ks < 4; ++ks) kfp[0][ks] = *(const bf16x8*)(kb_[0] + ks * 32);
#pragma unroll
    for (int i = 0; i < 5; ++i) {
      if (i < 4) {
#pragma unroll
        for (int ks = 0; ks < 4; ++ks)
          kfp[(i + 1) & 1][ks] = *(const bf16x8*)(kb_[i + 1] + ks * 32);
      }
      f32x4 a = (f32x4){0.f, 0.f, 0.f, 0.f};
#pragma unroll
      for (int ks = 0; ks < 4; ++ks)
        a = __builtin_amdgcn_mfma_f32_16x16x32_bf16(qf[ks], kfp[i & 1][ks], a, 0, 0, 0);
      int j = wave + 4 * i;
      if (j < 17) {
#pragma unroll
        for (int r = 0; r < 4; ++r) {
          int qrow = g * 4 + r;
          float vv = a[r] * 0.088388347648318447f;   // 1/sqrt(128)
          if (tok_[i] > t * 16 + qrow) vv = -1e10f;  // future mask
          lg[qrow][j * 16 + c] = vv;
        }
      }
    }
  }
  __syncthreads();

  // ---- softmax per q row: row r handled by 16 threads (col = tid&15)
  {
    const int r = tid >> 4, cc = tid & 15;
    float vals[17];
    float mx = -3.0e38f;
#pragma unroll
    for (int i = 0; i < 17; ++i) { vals[i] = lg[r][i * 16 + cc]; mx = fmaxf(mx, vals[i]); }
#pragma unroll
    for (int d = 1; d < 16; d <<= 1) mx = fmaxf(mx, __shfl_xor(mx, d, 64));
    float sum = 0.f;
#pragma unroll
    for (int i = 0; i < 17; ++i) { vals[i] = __expf(vals[i] - mx); sum += vals[i]; }
#pragma unroll
    for (int d = 1; d < 16; d <<= 1) sum += __shfl_xor(sum, d, 64);
    float inv = sum > 0.f ? 1.0f / sum : 0.f;
    u16* wrow = (u16*)&lg[r][0];
#pragma unroll
    for (int i = 0; i < 17; ++i) wrow[i * 16 + cc] = f2bf(vals[i] * inv);
    wrow[272 + cc] = 0;                        // zero the pad tile's weights
  }
  __syncthreads();

  // ---- PV: out(16x288 . 288x128); wave owns 32 dims; 1-ahead B-pair prefetch
  {
    f32x4 o0 = (f32x4){0.f, 0.f, 0.f, 0.f}, o1 = o0;
    const int d0 = wave * 32;
    const size_t hb = (size_t)h * 256;
    const int keyin = (g & 1) * 8;
    const u16* wrow = (const u16*)&lg[c][0];
    const u16* vb_[9];
#pragma unroll
    for (int ks = 0; ks < 9; ++ks) vb_[ks] = VT2 + (hb + tiles[2 * ks + (g >> 1)]) * 2048;
    bf16x8 pb0[2], pb1[2];
    pb0[0] = *(const bf16x8*)(vb_[0] + (d0 + c) * 16 + keyin);
    pb1[0] = *(const bf16x8*)(vb_[0] + (d0 + 16 + c) * 16 + keyin);
#pragma unroll
    for (int ks = 0; ks < 9; ++ks) {
      if (ks < 8) {
        pb0[(ks + 1) & 1] = *(const bf16x8*)(vb_[ks + 1] + (d0 + c) * 16 + keyin);
        pb1[(ks + 1) & 1] = *(const bf16x8*)(vb_[ks + 1] + (d0 + 16 + c) * 16 + keyin);
      }
      bf16x8 af = *(const bf16x8*)(wrow + ks * 32 + g * 8);
      o0 = __builtin_amdgcn_mfma_f32_16x16x32_bf16(af, pb0[ks & 1], o0, 0, 0, 0);
      o1 = __builtin_amdgcn_mfma_f32_16x16x32_bf16(af, pb1[ks & 1], o1, 0, 0, 0);
    }
#pragma unroll
    for (int r = 0; r < 4; ++r) {
      int qrow = g * 4 + r;
      size_t base = (size_t)(t * 16 + qrow) * 2048 + h * 128;
      Out[base + d0 + c]      = f2bf(o0[r]);
      Out[base + d0 + 16 + c] = f2bf(o1[r]);
    }
  }
}

extern "C" void kernel_launch(void* const* d_in, const int* in_sizes, int n_in,
                              void* d_out, int out_size, void* d_ws, size_t ws_size,
                              hipStream_t stream) {
  (void)in_sizes; (void)n_in; (void)out_size; (void)ws_size;
  const float* x      = (const float*)d_in[0];
  const float* Wq     = (const float*)d_in[1];
  const float* Wk     = (const float*)d_in[2];
  const float* Wv     = (const float*)d_in[3];
  const float* Wo     = (const float*)d_in[4];
  const float* freqs  = (const float*)d_in[5];
  const int* anchors  = (const int*)d_in[6];
  float* out = (float*)d_out;

  char* ws = (char*)d_ws;
  const size_t MB = 1024 * 1024;
  // Layout (98 MB used, aliasing dead buffers):
  //  0..16  : xbf, later attnb (x dead after QKV GEMM)
  // 16..40  : wqkvT contiguous; later Kp over 16..32 (dead after QKV GEMM)
  // 40..48  : woT (live until final GEMM)
  // 48..64  : qbf (un-rotated; attn applies q-RoPE)
  // 64..80  : kbf; later VT2 (kbf dead after prep2 writes Kp)
  // 80..96  : vbf
  // 96..98  : ct, st
  u16* xbf   = (u16*)(ws + 0);
  u16* wqkvT = (u16*)(ws + 16 * MB);   // (6144 x 2048) bf16, N x K
  u16* woT   = (u16*)(ws + 40 * MB);
  u16* qbf   = (u16*)(ws + 48 * MB);
  u16* kbf   = (u16*)(ws + 64 * MB);
  u16* vbf   = (u16*)(ws + 80 * MB);
  u16* attnb = (u16*)(ws + 0);
  u16* Kp    = (u16*)(ws + 16 * MB);
  u16* VT2   = (u16*)(ws + 64 * MB);
  float* ct  = (float*)(ws + 96 * MB);
  float* st  = (float*)(ws + 97 * MB);

  // prep1: weight transposes + x cast + trig table (one launch)
  prep1_kernel<<<25600, 256, 0, stream>>>(x, Wq, Wk, Wv, Wo, freqs,
                                          xbf, wqkvT, woT, ct, st);
  // fused QKV projection: 24x32 = 768 blocks = exactly 3 rounds at 1 block/CU
  gemm8p_kernel<2><<<dim3(24, 32), 512, 0, stream>>>(xbf, wqkvT, qbf, kbf, vbf,
                                                     4096, 6144, 2048);
  // prep2: k RoPE -> Kp + V repack (one launch); q stays un-rotated
  prep2_kernel<<<9216, 256, 0, stream>>>(kbf, Kp, vbf, VT2, ct, st);
  attn_kernel<<<dim3(256, 16), 256, 0, stream>>>(qbf, Kp, VT2, anchors, attnb, ct, st);
  // output projection: 8x32 = 256 blocks = exactly 1 round
  gemm8p_kernel<0><<<dim3(8, 32), 512, 0, stream>>>(attnb, woT, out, nullptr, nullptr,
                                                    4096, 2048, 2048);
}

// Round 8
// 251.137 us; speedup vs baseline: 1.0211x; 1.0211x over previous
//
#include <hip/hip_runtime.h>

typedef unsigned short u16;
typedef unsigned int u32;
typedef __attribute__((ext_vector_type(8))) short bf16x8;   // 8 bf16 in 4 VGPRs
typedef __attribute__((ext_vector_type(4))) float f32x4;

// ---------- bf16 helpers (RNE) ----------
__device__ __forceinline__ u16 f2bf(float f) {
  union { float f; u32 u; } v; v.f = f;
  u32 u = v.u;
  return (u16)((u + 0x7FFFu + ((u >> 16) & 1u)) >> 16);
}
__device__ __forceinline__ float bf2f(u16 s) {
  union { u32 u; float f; } v; v.u = ((u32)s) << 16;
  return v.f;
}

// ---------- async global->LDS (16B per lane) ----------
__device__ __forceinline__ void async16(const void* g, void* l) {
  __builtin_amdgcn_global_load_lds(
      (__attribute__((address_space(1))) void*)g,
      (__attribute__((address_space(3))) void*)l, 16, 0, 0);
}

// ---------- prep1: fused {4x weight transpose+cast, x cast, trig table} ----------
// transpose store phase vectorized: each thread packs 2 adjacent output cols
// into one u32 store (64B per 16 lanes -> 2x wider than scalar u16).
__global__ void prep1_kernel(const float* __restrict__ x,
                             const float* __restrict__ W0, const float* __restrict__ W1,
                             const float* __restrict__ W2, const float* __restrict__ W3,
                             const float* __restrict__ freqs,
                             u16* __restrict__ xbf, u16* __restrict__ wqkvT,
                             u16* __restrict__ woT,
                             float* __restrict__ ct, float* __restrict__ st) {
  __shared__ float tile[32][33];
  const int bid = blockIdx.x;
  const int tid = threadIdx.x;
  if (bid < 16384) {
    const int z = bid >> 12;
    const float* in = z == 0 ? W0 : z == 1 ? W1 : z == 2 ? W2 : W3;
    u16* out = z == 3 ? woT : wqkvT + (size_t)z * 4194304;
    const int local = bid & 4095;
    const int c0 = (local & 63) * 32, r0 = (local >> 6) * 32;
    const int tx = tid & 31, ty = tid >> 5;
#pragma unroll
    for (int i = ty; i < 32; i += 8) tile[i][tx] = in[(size_t)(r0 + i) * 2048 + c0 + tx];
    __syncthreads();
    const int cx = tid & 15, iy = tid >> 4;
#pragma unroll
    for (int i = iy; i < 32; i += 16) {
      u32 v = (u32)f2bf(tile[2 * cx][i]) | ((u32)f2bf(tile[2 * cx + 1][i]) << 16);
      *(u32*)(out + (size_t)(c0 + i) * 2048 + r0 + 2 * cx) = v;
    }
  } else if (bid < 24576) {
    int i = (bid - 16384) * 256 + tid;     // < 2097152
    float4 v = ((const float4*)x)[i];
    ushort4 o;
    o.x = f2bf(v.x); o.y = f2bf(v.y); o.z = f2bf(v.z); o.w = f2bf(v.w);
    ((ushort4*)xbf)[i] = o;
  } else {
    int i = (bid - 24576) * 256 + tid;     // < 262144
    float f = freqs[i];
    ct[i] = cosf(f); st[i] = sinf(f);
  }
}

// ---------- prep2: fused {k RoPE -> Kp [h][s][128], V repack -> VT2} ----------
// q is NOT rotated here; attn applies q-RoPE on load.
__global__ void prep2_kernel(const u16* __restrict__ k, u16* __restrict__ Kp,
                             const u16* __restrict__ Vin, u16* __restrict__ VT2,
                             const float* __restrict__ ct, const float* __restrict__ st) {
  __shared__ u16 lv[64][132];
  const int bid = blockIdx.x;
  const int tid = threadIdx.x;
  if (bid < 8192) {
    int i = bid * 256 + tid;                  // over S*H*32 = 2,097,152
    int dp = (i & 31) * 2;
    int hh = (i >> 5) & 15;
    int s  = i >> 9;
    float c0 = ct[s * 64 + dp], c1 = ct[s * 64 + dp + 1];
    float s0 = st[s * 64 + dp], s1 = st[s * 64 + dp + 1];
    size_t base = (size_t)s * 2048 + hh * 128 + dp;
    u32 lo = *(const u32*)(k + base);
    u32 hi = *(const u32*)(k + base + 64);
    float a0 = bf2f((u16)lo), a1 = bf2f((u16)(lo >> 16));
    float b0 = bf2f((u16)hi), b1 = bf2f((u16)(hi >> 16));
    u32 nlo = (u32)f2bf(a0 * c0 - b0 * s0) | ((u32)f2bf(a1 * c1 - b1 * s1) << 16);
    u32 nhi = (u32)f2bf(b0 * c0 + a0 * s0) | ((u32)f2bf(b1 * c1 + a1 * s1) << 16);
    size_t kpb = ((size_t)hh * 4096 + s) * 128 + dp;
    *(u32*)(Kp + kpb) = nlo;
    *(u32*)(Kp + kpb + 64) = nhi;
  } else {
    const int local = bid - 8192;             // 0..1023
    const int h = local >> 6;
    const int s0 = (local & 63) * 64;         // 4 tiles per block
#pragma unroll
    for (int i = 0; i < 16; ++i) {
      int idx = i * 256 + tid;
      int r = idx >> 6;
      int d2 = idx & 63;
      u32 vv = ((const u32*)Vin)[(size_t)(s0 + r) * 1024 + h * 64 + d2];
      *(u32*)(&lv[r][d2 * 2]) = vv;
    }
    __syncthreads();
#pragma unroll
    for (int i = 0; i < 16; ++i) {
      int idx = i * 256 + tid;               // 0..4095
      int k2 = idx & 7;                      // u32 over 2 keys
      int d  = (idx >> 3) & 127;
      int tl = idx >> 10;                    // local tile 0..3
      u32 lo = lv[tl * 16 + k2 * 2][d];
      u32 hi = lv[tl * 16 + k2 * 2 + 1][d];
      ((u32*)VT2)[(((size_t)h * 256 + (s0 >> 4) + tl) * 128 + d) * 8 + k2] = lo | (hi << 16);
    }
  }
}

// ---------- bf16 GEMM: C(MxN) = A(MxK) * Bt(NxK)^T, f32 accumulate ----------
// Proven structure (rounds 4/6: 1065 TF, MfmaUtil 49%): 128x128 tile, BK=64,
// 4 waves (2x2), single-buffer 32KB LDS, two __syncthreads per K-tile.
// MODE 0: f32 out. MODE 1: bf16 out. MODE 2: QKV-fused routing by col block.
template <int MODE>
__launch_bounds__(256, 2)
__global__ void gemm128_kernel(const u16* __restrict__ A, const u16* __restrict__ Bt,
                               void* __restrict__ C, u16* __restrict__ D1, u16* __restrict__ D2,
                               int M, int N, int K) {
  __shared__ __align__(16) u16 As[128 * 64];
  __shared__ __align__(16) u16 Bs[128 * 64];
  const int tid  = threadIdx.x;
  const int lane = tid & 63;
  const int wave = tid >> 6;
  const int wr = wave >> 1, wc = wave & 1;
  const int brow = blockIdx.y * 128;
  const int bcol = blockIdx.x * 128;

  int a_goff[4], b_goff[4], l_off[4];
#pragma unroll
  for (int i = 0; i < 4; ++i) {
    int p = (wave * 4 + i) * 1024 + lane * 16;        // linear byte in 16KB tile
    int row = p >> 7;                                 // 128B per row (64 bf16)
    int colb = (p & 127) ^ ((row & 7) << 4);          // inverse swizzle on source
    a_goff[i] = (brow + row) * K + (colb >> 1);
    b_goff[i] = (bcol + row) * K + (colb >> 1);
    l_off[i] = p;
  }

  f32x4 acc[4][4];
#pragma unroll
  for (int m = 0; m < 4; ++m)
#pragma unroll
    for (int n = 0; n < 4; ++n) acc[m][n] = (f32x4){0.f, 0.f, 0.f, 0.f};

  for (int k0 = 0; k0 < K; k0 += 64) {
#pragma unroll
    for (int i = 0; i < 4; ++i) {
      async16(A + a_goff[i] + k0, (char*)As + l_off[i]);
      async16(Bt + b_goff[i] + k0, (char*)Bs + l_off[i]);
    }
    __syncthreads();
#pragma unroll
    for (int kk = 0; kk < 2; ++kk) {
      bf16x8 af[4], bfr[4];
#pragma unroll
      for (int m = 0; m < 4; ++m) {
        int row = wr * 64 + m * 16 + (lane & 15);
        int byte = (row << 7) + ((kk * 64 + ((lane >> 4) << 4)) ^ ((row & 7) << 4));
        af[m] = *(const bf16x8*)((const char*)As + byte);
      }
#pragma unroll
      for (int n = 0; n < 4; ++n) {
        int row = wc * 64 + n * 16 + (lane & 15);
        int byte = (row << 7) + ((kk * 64 + ((lane >> 4) << 4)) ^ ((row & 7) << 4));
        bfr[n] = *(const bf16x8*)((const char*)Bs + byte);
      }
#pragma unroll
      for (int m = 0; m < 4; ++m)
#pragma unroll
        for (int n = 0; n < 4; ++n)
          acc[m][n] = __builtin_amdgcn_mfma_f32_16x16x32_bf16(af[m], bfr[n], acc[m][n], 0, 0, 0);
    }
    __syncthreads();
  }

  const int r0 = brow + wr * 64;
  const int c0 = bcol + wc * 64;
  if (MODE == 2) {
    const int sel = bcol >> 11;                       // block-uniform
    u16* dst = sel == 0 ? (u16*)C : sel == 1 ? D1 : D2;
    const int c0l = (bcol & 2047) + wc * 64;
#pragma unroll
    for (int m = 0; m < 4; ++m)
#pragma unroll
      for (int n = 0; n < 4; ++n)
#pragma unroll
        for (int r = 0; r < 4; ++r) {
          int rr = r0 + m * 16 + ((lane >> 4) << 2) + r;
          int cc = c0l + n * 16 + (lane & 15);
          dst[(size_t)rr * 2048 + cc] = f2bf(acc[m][n][r]);
        }
  } else {
#pragma unroll
    for (int m = 0; m < 4; ++m)
#pragma unroll
      for (int n = 0; n < 4; ++n)
#pragma unroll
        for (int r = 0; r < 4; ++r) {
          int rr = r0 + m * 16 + ((lane >> 4) << 2) + r;
          int cc = c0 + n * 16 + (lane & 15);
          if (MODE == 1) ((u16*)C)[(size_t)rr * N + cc] = f2bf(acc[m][n][r]);
          else           ((float*)C)[(size_t)rr * N + cc] = acc[m][n][r];
        }
  }
}

// ---------- sparse tile attention: one block per (tile t, head h) ----------
// Q loaded un-rotated; q-RoPE applied in-register (pairs d<->d+64 are in the
// same thread's qr[ks]/qr[ks^2]). K from Kp [h][s][128]; V from VT2.
// bf16 softmax weights overlay the f32 logits buffer row-aligned. LDS 17.9KB.
__launch_bounds__(256, 6)
__global__ void attn_kernel(const u16* __restrict__ Q, const u16* __restrict__ Kp,
                            const u16* __restrict__ VT2, const int* __restrict__ anchors,
                            u16* __restrict__ Out,
                            const float* __restrict__ ct, const float* __restrict__ st) {
  const int t = blockIdx.x;   // 0..255
  const int h = blockIdx.y;   // 0..15
  __shared__ int tiles[20];
  __shared__ __align__(16) float lg[16][280];    // logits; weights overlay per-row
  const int tid  = threadIdx.x;
  const int lane = tid & 63;
  const int wave = tid >> 6;
  const int g = lane >> 4;          // k-group 0..3
  const int c = lane & 15;

  if (tid < 16) tiles[tid] = anchors[(size_t)((h << 12) + (t * 16 + 15)) * 16 + tid];
  if (tid == 16) tiles[16] = t;            // local tile (order: anchors then local)
  if (tid >= 17 && tid < 20) tiles[tid] = 0;   // dummy tiles (results discarded)
  __syncthreads();

  // ---- QK with fused q-RoPE; 5 fixed iters/wave, 1-ahead K prefetch
  {
    const int s = t * 16 + c;
    const u16* qbase = Q + (size_t)s * 2048 + h * 128 + g * 8;
    bf16x8 qr[4];
#pragma unroll
    for (int ks = 0; ks < 4; ++ks) qr[ks] = *(const bf16x8*)(qbase + ks * 32);
    // rope tables for dmod64 in [g*8,g*8+8) and [32+g*8,32+g*8+8)
    float c0[8], s0[8], c1[8], s1[8];
    const float* ctb = ct + s * 64;
    const float* stb = st + s * 64;
    *(float4*)&c0[0] = *(const float4*)(ctb + g * 8);
    *(float4*)&c0[4] = *(const float4*)(ctb + g * 8 + 4);
    *(float4*)&c1[0] = *(const float4*)(ctb + 32 + g * 8);
    *(float4*)&c1[4] = *(const float4*)(ctb + 32 + g * 8 + 4);
    *(float4*)&s0[0] = *(const float4*)(stb + g * 8);
    *(float4*)&s0[4] = *(const float4*)(stb + g * 8 + 4);
    *(float4*)&s1[0] = *(const float4*)(stb + 32 + g * 8);
    *(float4*)&s1[4] = *(const float4*)(stb + 32 + g * 8 + 4);
    bf16x8 qf[4];
#pragma unroll
    for (int j = 0; j < 8; ++j) {
      float f0 = bf2f((u16)qr[0][j]), f1 = bf2f((u16)qr[1][j]);
      float f2 = bf2f((u16)qr[2][j]), f3 = bf2f((u16)qr[3][j]);
      qf[0][j] = (short)f2bf(f0 * c0[j] - f2 * s0[j]);
      qf[1][j] = (short)f2bf(f1 * c1[j] - f3 * s1[j]);
      qf[2][j] = (short)f2bf(f2 * c0[j] + f0 * s0[j]);
      qf[3][j] = (short)f2bf(f3 * c1[j] + f1 * s1[j]);
    }

    int tok_[5];
    const u16* kb_[5];
#pragma unroll
    for (int i = 0; i < 5; ++i) {
      int j = wave + 4 * i;                  // < 20
      tok_[i] = tiles[j] * 16 + c;
      kb_[i] = Kp + ((size_t)h * 4096 + tok_[i]) * 128 + g * 8;
    }
    bf16x8 kfp[2][4];
#pragma unroll
    for (int ks = 0; ks < 4; ++ks) kfp[0][ks] = *(const bf16x8*)(kb_[0] + ks * 32);
#pragma unroll
    for (int i = 0; i < 5; ++i) {
      if (i < 4) {
#pragma unroll
        for (int ks = 0; ks < 4; ++ks)
          kfp[(i + 1) & 1][ks] = *(const bf16x8*)(kb_[i + 1] + ks * 32);
      }
      f32x4 a = (f32x4){0.f, 0.f, 0.f, 0.f};
#pragma unroll
      for (int ks = 0; ks < 4; ++ks)
        a = __builtin_amdgcn_mfma_f32_16x16x32_bf16(qf[ks], kfp[i & 1][ks], a, 0, 0, 0);
      int j = wave + 4 * i;
      if (j < 17) {
#pragma unroll
        for (int r = 0; r < 4; ++r) {
          int qrow = g * 4 + r;
          float vv = a[r] * 0.088388347648318447f;   // 1/sqrt(128)
          if (tok_[i] > t * 16 + qrow) vv = -1e10f;  // future mask
          lg[qrow][j * 16 + c] = vv;
        }
      }
    }
  }
  __syncthreads();

  // ---- softmax per q row: row r handled by 16 threads (col = tid&15)
  {
    const int r = tid >> 4, cc = tid & 15;
    float vals[17];
    float mx = -3.0e38f;
#pragma unroll
    for (int i = 0; i < 17; ++i) { vals[i] = lg[r][i * 16 + cc]; mx = fmaxf(mx, vals[i]); }
#pragma unroll
    for (int d = 1; d < 16; d <<= 1) mx = fmaxf(mx, __shfl_xor(mx, d, 64));
    float sum = 0.f;
#pragma unroll
    for (int i = 0; i < 17; ++i) { vals[i] = __expf(vals[i] - mx); sum += vals[i]; }
#pragma unroll
    for (int d = 1; d < 16; d <<= 1) sum += __shfl_xor(sum, d, 64);
    float inv = sum > 0.f ? 1.0f / sum : 0.f;
    u16* wrow = (u16*)&lg[r][0];
#pragma unroll
    for (int i = 0; i < 17; ++i) wrow[i * 16 + cc] = f2bf(vals[i] * inv);
    wrow[272 + cc] = 0;                        // zero the pad tile's weights
  }
  __syncthreads();

  // ---- PV: out(16x288 . 288x128); wave owns 32 dims; 1-ahead B-pair prefetch
  {
    f32x4 o0 = (f32x4){0.f, 0.f, 0.f, 0.f}, o1 = o0;
    const int d0 = wave * 32;
    const size_t hb = (size_t)h * 256;
    const int keyin = (g & 1) * 8;
    const u16* wrow = (const u16*)&lg[c][0];
    const u16* vb_[9];
#pragma unroll
    for (int ks = 0; ks < 9; ++ks) vb_[ks] = VT2 + (hb + tiles[2 * ks + (g >> 1)]) * 2048;
    bf16x8 pb0[2], pb1[2];
    pb0[0] = *(const bf16x8*)(vb_[0] + (d0 + c) * 16 + keyin);
    pb1[0] = *(const bf16x8*)(vb_[0] + (d0 + 16 + c) * 16 + keyin);
#pragma unroll
    for (int ks = 0; ks < 9; ++ks) {
      if (ks < 8) {
        pb0[(ks + 1) & 1] = *(const bf16x8*)(vb_[ks + 1] + (d0 + c) * 16 + keyin);
        pb1[(ks + 1) & 1] = *(const bf16x8*)(vb_[ks + 1] + (d0 + 16 + c) * 16 + keyin);
      }
      bf16x8 af = *(const bf16x8*)(wrow + ks * 32 + g * 8);
      o0 = __builtin_amdgcn_mfma_f32_16x16x32_bf16(af, pb0[ks & 1], o0, 0, 0, 0);
      o1 = __builtin_amdgcn_mfma_f32_16x16x32_bf16(af, pb1[ks & 1], o1, 0, 0, 0);
    }
#pragma unroll
    for (int r = 0; r < 4; ++r) {
      int qrow = g * 4 + r;
      size_t base = (size_t)(t * 16 + qrow) * 2048 + h * 128;
      Out[base + d0 + c]      = f2bf(o0[r]);
      Out[base + d0 + 16 + c] = f2bf(o1[r]);
    }
  }
}

extern "C" void kernel_launch(void* const* d_in, const int* in_sizes, int n_in,
                              void* d_out, int out_size, void* d_ws, size_t ws_size,
                              hipStream_t stream) {
  (void)in_sizes; (void)n_in; (void)out_size; (void)ws_size;
  const float* x      = (const float*)d_in[0];
  const float* Wq     = (const float*)d_in[1];
  const float* Wk     = (const float*)d_in[2];
  const float* Wv     = (const float*)d_in[3];
  const float* Wo     = (const float*)d_in[4];
  const float* freqs  = (const float*)d_in[5];
  const int* anchors  = (const int*)d_in[6];
  float* out = (float*)d_out;

  char* ws = (char*)d_ws;
  const size_t MB = 1024 * 1024;
  // Layout (98 MB used, aliasing dead buffers):
  //  0..16  : xbf, later attnb (x dead after QKV GEMM)
  // 16..40  : wqkvT contiguous; later Kp over 16..32 (dead after QKV GEMM)
  // 40..48  : woT (live until final GEMM)
  // 48..64  : qbf (un-rotated; attn applies q-RoPE)
  // 64..80  : kbf; later VT2 (kbf dead after prep2 writes Kp)
  // 80..96  : vbf
  // 96..98  : ct, st
  u16* xbf   = (u16*)(ws + 0);
  u16* wqkvT = (u16*)(ws + 16 * MB);   // (6144 x 2048) bf16, N x K
  u16* woT   = (u16*)(ws + 40 * MB);
  u16* qbf   = (u16*)(ws + 48 * MB);
  u16* kbf   = (u16*)(ws + 64 * MB);
  u16* vbf   = (u16*)(ws + 80 * MB);
  u16* attnb = (u16*)(ws + 0);
  u16* Kp    = (u16*)(ws + 16 * MB);
  u16* VT2   = (u16*)(ws + 64 * MB);
  float* ct  = (float*)(ws + 96 * MB);
  float* st  = (float*)(ws + 97 * MB);

  // prep1: weight transposes + x cast + trig table (one launch)
  prep1_kernel<<<25600, 256, 0, stream>>>(x, Wq, Wk, Wv, Wo, freqs,
                                          xbf, wqkvT, woT, ct, st);
  // fused QKV projection: C = x(4096x2048) @ WqkvT(6144x2048)^T, routed epilogue
  gemm128_kernel<2><<<dim3(48, 32), 256, 0, stream>>>(xbf, wqkvT, qbf, kbf, vbf,
                                                      4096, 6144, 2048);
  // prep2: k RoPE -> Kp + V repack (one launch); q stays un-rotated
  prep2_kernel<<<9216, 256, 0, stream>>>(kbf, Kp, vbf, VT2, ct, st);
  attn_kernel<<<dim3(256, 16), 256, 0, stream>>>(qbf, Kp, VT2, anchors, attnb, ct, st);
  gemm128_kernel<0><<<dim3(16, 32), 256, 0, stream>>>(attnb, woT, out, nullptr, nullptr,
                                                      4096, 2048, 2048);
}

// Round 9
// 239.003 us; speedup vs baseline: 1.0730x; 1.0508x over previous
//
#include <hip/hip_runtime.h>

typedef unsigned short u16;
typedef unsigned int u32;
typedef __attribute__((ext_vector_type(8))) short bf16x8;   // 8 bf16 in 4 VGPRs
typedef __attribute__((ext_vector_type(4))) float f32x4;

// ---------- bf16 helpers (RNE) ----------
__device__ __forceinline__ u16 f2bf(float f) {
  union { float f; u32 u; } v; v.f = f;
  u32 u = v.u;
  return (u16)((u + 0x7FFFu + ((u >> 16) & 1u)) >> 16);
}
__device__ __forceinline__ float bf2f(u16 s) {
  union { u32 u; float f; } v; v.u = ((u32)s) << 16;
  return v.f;
}

// ---------- async global->LDS (16B per lane) ----------
__device__ __forceinline__ void async16(const void* g, void* l) {
  __builtin_amdgcn_global_load_lds(
      (__attribute__((address_space(1))) void*)g,
      (__attribute__((address_space(3))) void*)l, 16, 0, 0);
}

// ---------- prep1: fused {4x weight transpose+cast, x cast, trig table} ----------
__global__ void prep1_kernel(const float* __restrict__ x,
                             const float* __restrict__ W0, const float* __restrict__ W1,
                             const float* __restrict__ W2, const float* __restrict__ W3,
                             const float* __restrict__ freqs,
                             u16* __restrict__ xbf, u16* __restrict__ wqkvT,
                             u16* __restrict__ woT,
                             float* __restrict__ ct, float* __restrict__ st) {
  __shared__ float tile[32][33];
  const int bid = blockIdx.x;
  const int tid = threadIdx.x;
  if (bid < 16384) {
    const int z = bid >> 12;
    const float* in = z == 0 ? W0 : z == 1 ? W1 : z == 2 ? W2 : W3;
    u16* out = z == 3 ? woT : wqkvT + (size_t)z * 4194304;
    const int local = bid & 4095;
    const int c0 = (local & 63) * 32, r0 = (local >> 6) * 32;
    const int tx = tid & 31, ty = tid >> 5;
#pragma unroll
    for (int i = ty; i < 32; i += 8) tile[i][tx] = in[(size_t)(r0 + i) * 2048 + c0 + tx];
    __syncthreads();
    const int cx = tid & 15, iy = tid >> 4;
#pragma unroll
    for (int i = iy; i < 32; i += 16) {
      u32 v = (u32)f2bf(tile[2 * cx][i]) | ((u32)f2bf(tile[2 * cx + 1][i]) << 16);
      *(u32*)(out + (size_t)(c0 + i) * 2048 + r0 + 2 * cx) = v;
    }
  } else if (bid < 24576) {
    int i = (bid - 16384) * 256 + tid;     // < 2097152
    float4 v = ((const float4*)x)[i];
    ushort4 o;
    o.x = f2bf(v.x); o.y = f2bf(v.y); o.z = f2bf(v.z); o.w = f2bf(v.w);
    ((ushort4*)xbf)[i] = o;
  } else {
    int i = (bid - 24576) * 256 + tid;     // < 262144
    float f = freqs[i];
    ct[i] = cosf(f); st[i] = sinf(f);
  }
}

// ---------- prep2: fused {RoPE (q in-place, k->Kp [h][s][128]), V repack} ----------
__global__ void prep2_kernel(u16* __restrict__ q, const u16* __restrict__ k,
                             u16* __restrict__ Kp,
                             const u16* __restrict__ Vin, u16* __restrict__ VT2,
                             const float* __restrict__ ct, const float* __restrict__ st) {
  __shared__ u16 lv[64][132];
  const int bid = blockIdx.x;
  const int tid = threadIdx.x;
  if (bid < 8192) {
    int i = bid * 256 + tid;                  // over S*H*32 = 2,097,152
    int dp = (i & 31) * 2;
    int hh = (i >> 5) & 15;
    int s  = i >> 9;
    float c0 = ct[s * 64 + dp], c1 = ct[s * 64 + dp + 1];
    float s0 = st[s * 64 + dp], s1 = st[s * 64 + dp + 1];
    size_t base = (size_t)s * 2048 + hh * 128 + dp;
    {
      u32 lo = *(u32*)(q + base);
      u32 hi = *(u32*)(q + base + 64);
      float a0 = bf2f((u16)lo), a1 = bf2f((u16)(lo >> 16));
      float b0 = bf2f((u16)hi), b1 = bf2f((u16)(hi >> 16));
      u32 nlo = (u32)f2bf(a0 * c0 - b0 * s0) | ((u32)f2bf(a1 * c1 - b1 * s1) << 16);
      u32 nhi = (u32)f2bf(b0 * c0 + a0 * s0) | ((u32)f2bf(b1 * c1 + a1 * s1) << 16);
      *(u32*)(q + base) = nlo;
      *(u32*)(q + base + 64) = nhi;
    }
    {
      u32 lo = *(const u32*)(k + base);
      u32 hi = *(const u32*)(k + base + 64);
      float a0 = bf2f((u16)lo), a1 = bf2f((u16)(lo >> 16));
      float b0 = bf2f((u16)hi), b1 = bf2f((u16)(hi >> 16));
      u32 nlo = (u32)f2bf(a0 * c0 - b0 * s0) | ((u32)f2bf(a1 * c1 - b1 * s1) << 16);
      u32 nhi = (u32)f2bf(b0 * c0 + a0 * s0) | ((u32)f2bf(b1 * c1 + a1 * s1) << 16);
      size_t kpb = ((size_t)hh * 4096 + s) * 128 + dp;
      *(u32*)(Kp + kpb) = nlo;
      *(u32*)(Kp + kpb + 64) = nhi;
    }
  } else {
    const int local = bid - 8192;             // 0..1023
    const int h = local >> 6;
    const int s0 = (local & 63) * 64;         // 4 tiles per block
#pragma unroll
    for (int i = 0; i < 16; ++i) {
      int idx = i * 256 + tid;
      int r = idx >> 6;
      int d2 = idx & 63;
      u32 vv = ((const u32*)Vin)[(size_t)(s0 + r) * 1024 + h * 64 + d2];
      *(u32*)(&lv[r][d2 * 2]) = vv;
    }
    __syncthreads();
#pragma unroll
    for (int i = 0; i < 16; ++i) {
      int idx = i * 256 + tid;               // 0..4095
      int k2 = idx & 7;                      // u32 over 2 keys
      int d  = (idx >> 3) & 127;
      int tl = idx >> 10;                    // local tile 0..3
      u32 lo = lv[tl * 16 + k2 * 2][d];
      u32 hi = lv[tl * 16 + k2 * 2 + 1][d];
      ((u32*)VT2)[(((size_t)h * 256 + (s0 >> 4) + tl) * 128 + d) * 8 + k2] = lo | (hi << 16);
    }
  }
}

// ---------- bf16 GEMM: C(MxN) = A(MxK) * Bt(NxK)^T, f32 accumulate ----------
// Proven 2-barrier structure, now BK=128 (two 64-col halves per barrier pair):
// 16 global_load_lds + 64 MFMA per pair -> half the barrier-drain frequency.
// LDS 64 KB, still 2 blocks/CU (launch_bounds cap). Zero bank conflicts.
// MODE 0: f32 out. MODE 1: bf16 out. MODE 2: QKV-fused routing by col block.
template <int MODE>
__launch_bounds__(256, 2)
__global__ void gemm128_kernel(const u16* __restrict__ A, const u16* __restrict__ Bt,
                               void* __restrict__ C, u16* __restrict__ D1, u16* __restrict__ D2,
                               int M, int N, int K) {
  __shared__ __align__(16) u16 As[2][128 * 64];
  __shared__ __align__(16) u16 Bs[2][128 * 64];
  const int tid  = threadIdx.x;
  const int lane = tid & 63;
  const int wave = tid >> 6;
  const int wr = wave >> 1, wc = wave & 1;
  const int brow = blockIdx.y * 128;
  const int bcol = blockIdx.x * 128;

  int a_goff[4], b_goff[4], l_off[4];
#pragma unroll
  for (int i = 0; i < 4; ++i) {
    int p = (wave * 4 + i) * 1024 + lane * 16;        // linear byte in 16KB tile
    int row = p >> 7;                                 // 128B per row (64 bf16)
    int colb = (p & 127) ^ ((row & 7) << 4);          // inverse swizzle on source
    a_goff[i] = (brow + row) * K + (colb >> 1);
    b_goff[i] = (bcol + row) * K + (colb >> 1);
    l_off[i] = p;
  }

  f32x4 acc[4][4];
#pragma unroll
  for (int m = 0; m < 4; ++m)
#pragma unroll
    for (int n = 0; n < 4; ++n) acc[m][n] = (f32x4){0.f, 0.f, 0.f, 0.f};

  for (int k0 = 0; k0 < K; k0 += 128) {
#pragma unroll
    for (int i = 0; i < 4; ++i) {
      async16(A + a_goff[i] + k0, (char*)As[0] + l_off[i]);
      async16(Bt + b_goff[i] + k0, (char*)Bs[0] + l_off[i]);
    }
#pragma unroll
    for (int i = 0; i < 4; ++i) {
      async16(A + a_goff[i] + k0 + 64, (char*)As[1] + l_off[i]);
      async16(Bt + b_goff[i] + k0 + 64, (char*)Bs[1] + l_off[i]);
    }
    __syncthreads();
#pragma unroll
    for (int half = 0; half < 2; ++half) {
#pragma unroll
      for (int kk = 0; kk < 2; ++kk) {
        bf16x8 af[4], bfr[4];
#pragma unroll
        for (int m = 0; m < 4; ++m) {
          int row = wr * 64 + m * 16 + (lane & 15);
          int byte = (row << 7) + ((kk * 64 + ((lane >> 4) << 4)) ^ ((row & 7) << 4));
          af[m] = *(const bf16x8*)((const char*)As[half] + byte);
        }
#pragma unroll
        for (int n = 0; n < 4; ++n) {
          int row = wc * 64 + n * 16 + (lane & 15);
          int byte = (row << 7) + ((kk * 64 + ((lane >> 4) << 4)) ^ ((row & 7) << 4));
          bfr[n] = *(const bf16x8*)((const char*)Bs[half] + byte);
        }
#pragma unroll
        for (int m = 0; m < 4; ++m)
#pragma unroll
          for (int n = 0; n < 4; ++n)
            acc[m][n] = __builtin_amdgcn_mfma_f32_16x16x32_bf16(af[m], bfr[n], acc[m][n], 0, 0, 0);
      }
    }
    __syncthreads();
  }

  const int r0 = brow + wr * 64;
  const int c0 = bcol + wc * 64;
  if (MODE == 2) {
    const int sel = bcol >> 11;                       // block-uniform
    u16* dst = sel == 0 ? (u16*)C : sel == 1 ? D1 : D2;
    const int c0l = (bcol & 2047) + wc * 64;
#pragma unroll
    for (int m = 0; m < 4; ++m)
#pragma unroll
      for (int n = 0; n < 4; ++n)
#pragma unroll
        for (int r = 0; r < 4; ++r) {
          int rr = r0 + m * 16 + ((lane >> 4) << 2) + r;
          int cc = c0l + n * 16 + (lane & 15);
          dst[(size_t)rr * 2048 + cc] = f2bf(acc[m][n][r]);
        }
  } else {
#pragma unroll
    for (int m = 0; m < 4; ++m)
#pragma unroll
      for (int n = 0; n < 4; ++n)
#pragma unroll
        for (int r = 0; r < 4; ++r) {
          int rr = r0 + m * 16 + ((lane >> 4) << 2) + r;
          int cc = c0 + n * 16 + (lane & 15);
          if (MODE == 1) ((u16*)C)[(size_t)rr * N + cc] = f2bf(acc[m][n][r]);
          else           ((float*)C)[(size_t)rr * N + cc] = acc[m][n][r];
        }
  }
}

// ---------- sparse tile attention: one block per (tile t, head h) ----------
// 17 key tiles (16 anchors + local) padded to 20; 272 keys padded to 288 with
// zero weights. Q pre-rotated. K from Kp [h][s][128]; V from VT2 [h][tile][d][16].
// bf16 softmax weights overlay the f32 logits buffer row-aligned (1168B rows:
// PV read start-banks are 2-way aliased = free). LDS 18.7KB.
__launch_bounds__(256, 8)
__global__ void attn_kernel(const u16* __restrict__ Q, const u16* __restrict__ Kp,
                            const u16* __restrict__ VT2, const int* __restrict__ anchors,
                            u16* __restrict__ Out) {
  const int t = blockIdx.x;   // 0..255
  const int h = blockIdx.y;   // 0..15
  __shared__ int tiles[20];
  __shared__ __align__(16) float lg[16][292];    // logits; weights overlay per-row
  const int tid  = threadIdx.x;
  const int lane = tid & 63;
  const int wave = tid >> 6;
  const int g = lane >> 4;          // k-group 0..3
  const int c = lane & 15;

  if (tid < 16) tiles[tid] = anchors[(size_t)((h << 12) + (t * 16 + 15)) * 16 + tid];
  if (tid == 16) tiles[16] = t;            // local tile (order: anchors then local)
  if (tid >= 17 && tid < 20) tiles[tid] = 0;   // dummy tiles (results discarded)
  __syncthreads();

  // ---- QK: Q(16x128) . K_tile(16x128)^T; 5 fixed iters/wave, 1-ahead prefetch
  {
    const u16* qbase = Q + (size_t)(t * 16 + c) * 2048 + h * 128 + g * 8;
    bf16x8 qf[4];
#pragma unroll
    for (int ks = 0; ks < 4; ++ks) qf[ks] = *(const bf16x8*)(qbase + ks * 32);

    int tok_[5];
    const u16* kb_[5];
#pragma unroll
    for (int i = 0; i < 5; ++i) {
      int j = wave + 4 * i;                  // < 20
      tok_[i] = tiles[j] * 16 + c;
      kb_[i] = Kp + ((size_t)h * 4096 + tok_[i]) * 128 + g * 8;
    }
    bf16x8 kfp[2][4];
#pragma unroll
    for (int ks = 0; ks < 4; ++ks) kfp[0][ks] = *(const bf16x8*)(kb_[0] + ks * 32);
#pragma unroll
    for (int i = 0; i < 5; ++i) {
      if (i < 4) {
#pragma unroll
        for (int ks = 0; ks < 4; ++ks)
          kfp[(i + 1) & 1][ks] = *(const bf16x8*)(kb_[i + 1] + ks * 32);
      }
      f32x4 a = (f32x4){0.f, 0.f, 0.f, 0.f};
#pragma unroll
      for (int ks = 0; ks < 4; ++ks)
        a = __builtin_amdgcn_mfma_f32_16x16x32_bf16(qf[ks], kfp[i & 1][ks], a, 0, 0, 0);
      int j = wave + 4 * i;
      if (j < 17) {
#pragma unroll
        for (int r = 0; r < 4; ++r) {
          int qrow = g * 4 + r;
          float vv = a[r] * 0.088388347648318447f;   // 1/sqrt(128)
          if (tok_[i] > t * 16 + qrow) vv = -1e10f;  // future mask
          lg[qrow][j * 16 + c] = vv;
        }
      }
    }
  }
  __syncthreads();

  // ---- softmax per q row: row r handled by 16 threads (col = tid&15)
  {
    const int r = tid >> 4, cc = tid & 15;
    float vals[17];
    float mx = -3.0e38f;
#pragma unroll
    for (int i = 0; i < 17; ++i) { vals[i] = lg[r][i * 16 + cc]; mx = fmaxf(mx, vals[i]); }
#pragma unroll
    for (int d = 1; d < 16; d <<= 1) mx = fmaxf(mx, __shfl_xor(mx, d, 64));
    float sum = 0.f;
#pragma unroll
    for (int i = 0; i < 17; ++i) { vals[i] = __expf(vals[i] - mx); sum += vals[i]; }
#pragma unroll
    for (int d = 1; d < 16; d <<= 1) sum += __shfl_xor(sum, d, 64);
    float inv = sum > 0.f ? 1.0f / sum : 0.f;
    u16* wrow = (u16*)&lg[r][0];
#pragma unroll
    for (int i = 0; i < 17; ++i) wrow[i * 16 + cc] = f2bf(vals[i] * inv);
    wrow[272 + cc] = 0;                        // zero the pad tile's weights
  }
  __syncthreads();

  // ---- PV: out(16x288 . 288x128); wave owns 32 dims; 1-ahead B-pair prefetch
  {
    f32x4 o0 = (f32x4){0.f, 0.f, 0.f, 0.f}, o1 = o0;
    const int d0 = wave * 32;
    const size_t hb = (size_t)h * 256;
    const int keyin = (g & 1) * 8;
    const u16* wrow = (const u16*)&lg[c][0];
    const u16* vb_[9];
#pragma unroll
    for (int ks = 0; ks < 9; ++ks) vb_[ks] = VT2 + (hb + tiles[2 * ks + (g >> 1)]) * 2048;
    bf16x8 pb0[2], pb1[2];
    pb0[0] = *(const bf16x8*)(vb_[0] + (d0 + c) * 16 + keyin);
    pb1[0] = *(const bf16x8*)(vb_[0] + (d0 + 16 + c) * 16 + keyin);
#pragma unroll
    for (int ks = 0; ks < 9; ++ks) {
      if (ks < 8) {
        pb0[(ks + 1) & 1] = *(const bf16x8*)(vb_[ks + 1] + (d0 + c) * 16 + keyin);
        pb1[(ks + 1) & 1] = *(const bf16x8*)(vb_[ks + 1] + (d0 + 16 + c) * 16 + keyin);
      }
      bf16x8 af = *(const bf16x8*)(wrow + ks * 32 + g * 8);
      o0 = __builtin_amdgcn_mfma_f32_16x16x32_bf16(af, pb0[ks & 1], o0, 0, 0, 0);
      o1 = __builtin_amdgcn_mfma_f32_16x16x32_bf16(af, pb1[ks & 1], o1, 0, 0, 0);
    }
#pragma unroll
    for (int r = 0; r < 4; ++r) {
      int qrow = g * 4 + r;
      size_t base = (size_t)(t * 16 + qrow) * 2048 + h * 128;
      Out[base + d0 + c]      = f2bf(o0[r]);
      Out[base + d0 + 16 + c] = f2bf(o1[r]);
    }
  }
}

extern "C" void kernel_launch(void* const* d_in, const int* in_sizes, int n_in,
                              void* d_out, int out_size, void* d_ws, size_t ws_size,
                              hipStream_t stream) {
  (void)in_sizes; (void)n_in; (void)out_size; (void)ws_size;
  const float* x      = (const float*)d_in[0];
  const float* Wq     = (const float*)d_in[1];
  const float* Wk     = (const float*)d_in[2];
  const float* Wv     = (const float*)d_in[3];
  const float* Wo     = (const float*)d_in[4];
  const float* freqs  = (const float*)d_in[5];
  const int* anchors  = (const int*)d_in[6];
  float* out = (float*)d_out;

  char* ws = (char*)d_ws;
  const size_t MB = 1024 * 1024;
  // Layout (98 MB used, aliasing dead buffers):
  //  0..16  : xbf, later attnb (x dead after QKV GEMM)
  // 16..40  : wqkvT contiguous; later Kp over 16..32 (dead after QKV GEMM)
  // 40..48  : woT (live until final GEMM)
  // 48..64  : qbf (rotated in-place by prep2)
  // 64..80  : kbf; later VT2 (kbf dead after prep2 writes Kp)
  // 80..96  : vbf
  // 96..98  : ct, st
  u16* xbf   = (u16*)(ws + 0);
  u16* wqkvT = (u16*)(ws + 16 * MB);   // (6144 x 2048) bf16, N x K
  u16* woT   = (u16*)(ws + 40 * MB);
  u16* qbf   = (u16*)(ws + 48 * MB);
  u16* kbf   = (u16*)(ws + 64 * MB);
  u16* vbf   = (u16*)(ws + 80 * MB);
  u16* attnb = (u16*)(ws + 0);
  u16* Kp    = (u16*)(ws + 16 * MB);
  u16* VT2   = (u16*)(ws + 64 * MB);
  float* ct  = (float*)(ws + 96 * MB);
  float* st  = (float*)(ws + 97 * MB);

  // prep1: weight transposes + x cast + trig table (one launch)
  prep1_kernel<<<25600, 256, 0, stream>>>(x, Wq, Wk, Wv, Wo, freqs,
                                          xbf, wqkvT, woT, ct, st);
  // fused QKV projection: C = x(4096x2048) @ WqkvT(6144x2048)^T, routed epilogue
  gemm128_kernel<2><<<dim3(48, 32), 256, 0, stream>>>(xbf, wqkvT, qbf, kbf, vbf,
                                                      4096, 6144, 2048);
  // prep2: RoPE (q in-place, k->Kp) + V repack (one launch)
  prep2_kernel<<<9216, 256, 0, stream>>>(qbf, kbf, Kp, vbf, VT2, ct, st);
  attn_kernel<<<dim3(256, 16), 256, 0, stream>>>(qbf, Kp, VT2, anchors, attnb);
  gemm128_kernel<0><<<dim3(16, 32), 256, 0, stream>>>(attnb, woT, out, nullptr, nullptr,
                                                      4096, 2048, 2048);
}

// Round 10
// 230.272 us; speedup vs baseline: 1.1137x; 1.0379x over previous
//
#include <hip/hip_runtime.h>

typedef unsigned short u16;
typedef unsigned int u32;
typedef __attribute__((ext_vector_type(8))) short bf16x8;   // 8 bf16 in 4 VGPRs
typedef __attribute__((ext_vector_type(4))) float f32x4;

// ---------- bf16 helpers (RNE) ----------
__device__ __forceinline__ u16 f2bf(float f) {
  union { float f; u32 u; } v; v.f = f;
  u32 u = v.u;
  return (u16)((u + 0x7FFFu + ((u >> 16) & 1u)) >> 16);
}
__device__ __forceinline__ float bf2f(u16 s) {
  union { u32 u; float f; } v; v.u = ((u32)s) << 16;
  return v.f;
}

// ---------- async global->LDS (16B per lane) ----------
__device__ __forceinline__ void async16(const void* g, void* l) {
  __builtin_amdgcn_global_load_lds(
      (__attribute__((address_space(1))) void*)g,
      (__attribute__((address_space(3))) void*)l, 16, 0, 0);
}

// ---------- prep1: fused {4x weight transpose+cast, x cast, trig table} ----------
__global__ void prep1_kernel(const float* __restrict__ x,
                             const float* __restrict__ W0, const float* __restrict__ W1,
                             const float* __restrict__ W2, const float* __restrict__ W3,
                             const float* __restrict__ freqs,
                             u16* __restrict__ xbf, u16* __restrict__ wqkvT,
                             u16* __restrict__ woT,
                             float* __restrict__ ct, float* __restrict__ st) {
  __shared__ float tile[32][33];
  const int bid = blockIdx.x;
  const int tid = threadIdx.x;
  if (bid < 16384) {
    const int z = bid >> 12;
    const float* in = z == 0 ? W0 : z == 1 ? W1 : z == 2 ? W2 : W3;
    u16* out = z == 3 ? woT : wqkvT + (size_t)z * 4194304;
    const int local = bid & 4095;
    const int c0 = (local & 63) * 32, r0 = (local >> 6) * 32;
    const int tx = tid & 31, ty = tid >> 5;
#pragma unroll
    for (int i = ty; i < 32; i += 8) tile[i][tx] = in[(size_t)(r0 + i) * 2048 + c0 + tx];
    __syncthreads();
    const int cx = tid & 15, iy = tid >> 4;
#pragma unroll
    for (int i = iy; i < 32; i += 16) {
      u32 v = (u32)f2bf(tile[2 * cx][i]) | ((u32)f2bf(tile[2 * cx + 1][i]) << 16);
      *(u32*)(out + (size_t)(c0 + i) * 2048 + r0 + 2 * cx) = v;
    }
  } else if (bid < 24576) {
    int i = (bid - 16384) * 256 + tid;     // < 2097152
    float4 v = ((const float4*)x)[i];
    ushort4 o;
    o.x = f2bf(v.x); o.y = f2bf(v.y); o.z = f2bf(v.z); o.w = f2bf(v.w);
    ((ushort4*)xbf)[i] = o;
  } else {
    int i = (bid - 24576) * 256 + tid;     // < 262144
    float f = freqs[i];
    ct[i] = cosf(f); st[i] = sinf(f);
  }
}

// ---------- bf16 GEMM: C(MxN) = A(MxK) * Bt(NxK)^T, f32 accumulate ----------
// K-loop: proven 97us structure (128x128 tile, BK=64, 4 waves 2x2, single-buffer
// LDS, two __syncthreads per K-tile, zero bank conflicts).
// MODE 0: plain f32 out (Wo). MODE 2: QKV-fused epilogue -- each block covers
// 128 tokens x one full head; epilogue bounces acc through padded LDS
// ([64][129] f32) and emits: q -> rope -> C (S,2048); k -> rope -> D1 = Kp
// [h][s][128]; v -> transpose -> D2 = VT2 [h][tile][d][16]. prep2 eliminated.
template <int MODE>
__launch_bounds__(256, 2)
__global__ void gemm128_kernel(const u16* __restrict__ A, const u16* __restrict__ Bt,
                               void* __restrict__ C, u16* __restrict__ D1, u16* __restrict__ D2,
                               const float* __restrict__ ct, const float* __restrict__ st,
                               int M, int N, int K) {
  __shared__ __align__(16) char smem[33152];   // K-loop: As(16K)+Bs(16K); epilogue: f32[64][129]
  u16* As = (u16*)smem;
  u16* Bs = (u16*)(smem + 16384);
  const int tid  = threadIdx.x;
  const int lane = tid & 63;
  const int wave = tid >> 6;
  const int wr = wave >> 1, wc = wave & 1;
  const int brow = blockIdx.y * 128;
  const int bcol = blockIdx.x * 128;

  int a_goff[4], b_goff[4], l_off[4];
#pragma unroll
  for (int i = 0; i < 4; ++i) {
    int p = (wave * 4 + i) * 1024 + lane * 16;        // linear byte in 16KB tile
    int row = p >> 7;                                 // 128B per row (64 bf16)
    int colb = (p & 127) ^ ((row & 7) << 4);          // inverse swizzle on source
    a_goff[i] = (brow + row) * K + (colb >> 1);
    b_goff[i] = (bcol + row) * K + (colb >> 1);
    l_off[i] = p;
  }

  f32x4 acc[4][4];
#pragma unroll
  for (int m = 0; m < 4; ++m)
#pragma unroll
    for (int n = 0; n < 4; ++n) acc[m][n] = (f32x4){0.f, 0.f, 0.f, 0.f};

  for (int k0 = 0; k0 < K; k0 += 64) {
#pragma unroll
    for (int i = 0; i < 4; ++i) {
      async16(A + a_goff[i] + k0, (char*)As + l_off[i]);
      async16(Bt + b_goff[i] + k0, (char*)Bs + l_off[i]);
    }
    __syncthreads();
#pragma unroll
    for (int kk = 0; kk < 2; ++kk) {
      bf16x8 af[4], bfr[4];
#pragma unroll
      for (int m = 0; m < 4; ++m) {
        int row = wr * 64 + m * 16 + (lane & 15);
        int byte = (row << 7) + ((kk * 64 + ((lane >> 4) << 4)) ^ ((row & 7) << 4));
        af[m] = *(const bf16x8*)((const char*)As + byte);
      }
#pragma unroll
      for (int n = 0; n < 4; ++n) {
        int row = wc * 64 + n * 16 + (lane & 15);
        int byte = (row << 7) + ((kk * 64 + ((lane >> 4) << 4)) ^ ((row & 7) << 4));
        bfr[n] = *(const bf16x8*)((const char*)Bs + byte);
      }
#pragma unroll
      for (int m = 0; m < 4; ++m)
#pragma unroll
        for (int n = 0; n < 4; ++n)
          acc[m][n] = __builtin_amdgcn_mfma_f32_16x16x32_bf16(af[m], bfr[n], acc[m][n], 0, 0, 0);
    }
    __syncthreads();
  }

  if (MODE == 2) {
    // ---- fused epilogue: rope(q,k) / transpose(v), via padded LDS bounce ----
    const int sel = bcol >> 11;                       // 0=q 1=k 2=v (block-uniform)
    const int hh  = (bcol & 2047) >> 7;               // head index
    float* ep = (float*)smem;                         // [64][129]
#pragma unroll
    for (int half = 0; half < 2; ++half) {
      if (wr == half) {
#pragma unroll
        for (int m = 0; m < 4; ++m)
#pragma unroll
          for (int n = 0; n < 4; ++n)
#pragma unroll
            for (int r = 0; r < 4; ++r) {
              int lr = m * 16 + ((lane >> 4) << 2) + r;     // 0..63
              int lc = wc * 64 + n * 16 + (lane & 15);      // 0..127
              ep[lr * 129 + lc] = acc[m][n][r];
            }
      }
      __syncthreads();
      const int rowbase = brow + half * 64;
      if (sel == 2) {
        // v: transpose 64 tokens (4 tiles) x 128 dims -> VT2[h][tile][d][16]
#pragma unroll
        for (int it = 0; it < 16; ++it) {
          int idx = it * 256 + tid;          // 0..4095
          int tl = idx >> 10;                // local tile 0..3
          int d  = (idx >> 3) & 127;
          int k2 = idx & 7;                  // u32 over 2 keys
          u32 lo = f2bf(ep[(tl * 16 + 2 * k2) * 129 + d]);
          u32 hi = f2bf(ep[(tl * 16 + 2 * k2 + 1) * 129 + d]);
          int tile = (rowbase >> 4) + tl;
          *(u32*)(D2 + (((size_t)(hh * 256 + tile) * 128 + d) * 16 + 2 * k2)) = lo | (hi << 16);
        }
      } else {
        // q/k: rope pairs (d, d+64), d even -> two u32 stores per thread-iter
#pragma unroll
        for (int it = 0; it < 8; ++it) {
          int idx = it * 256 + tid;          // 0..2047
          int row = idx >> 5;                // 0..63
          int d = (idx & 31) * 2;            // 0..62
          int t = rowbase + row;
          float a0 = ep[row * 129 + d],      a1 = ep[row * 129 + d + 1];
          float b0 = ep[row * 129 + d + 64], b1 = ep[row * 129 + d + 65];
          float cc0 = ct[t * 64 + d], cc1 = ct[t * 64 + d + 1];
          float ss0 = st[t * 64 + d], ss1 = st[t * 64 + d + 1];
          u32 lo = (u32)f2bf(a0 * cc0 - b0 * ss0) | ((u32)f2bf(a1 * cc1 - b1 * ss1) << 16);
          u32 hi = (u32)f2bf(b0 * cc0 + a0 * ss0) | ((u32)f2bf(b1 * cc1 + a1 * ss1) << 16);
          if (sel == 0) {
            u16* qd = (u16*)C + (size_t)t * 2048 + hh * 128 + d;
            *(u32*)qd = lo;
            *(u32*)(qd + 64) = hi;
          } else {
            u16* kd = D1 + ((size_t)hh * 4096 + t) * 128 + d;
            *(u32*)kd = lo;
            *(u32*)(kd + 64) = hi;
          }
        }
      }
      __syncthreads();
    }
  } else {
    const int r0 = brow + wr * 64;
    const int c0 = bcol + wc * 64;
#pragma unroll
    for (int m = 0; m < 4; ++m)
#pragma unroll
      for (int n = 0; n < 4; ++n)
#pragma unroll
        for (int r = 0; r < 4; ++r) {
          int rr = r0 + m * 16 + ((lane >> 4) << 2) + r;
          int cc = c0 + n * 16 + (lane & 15);
          ((float*)C)[(size_t)rr * N + cc] = acc[m][n][r];
        }
  }
}

// ---------- sparse tile attention: one block per (tile t, head h) ----------
// 17 key tiles (16 anchors + local) padded to 20; 272 keys padded to 288 with
// zero weights. Q pre-rotated (S,2048). K from Kp [h][s][128]; V from VT2
// [h][tile][d][16]. bf16 softmax weights overlay the f32 logits buffer
// row-aligned (1168B rows: PV start-banks 2-way aliased = free). LDS 18.7KB.
__launch_bounds__(256, 6)
__global__ void attn_kernel(const u16* __restrict__ Q, const u16* __restrict__ Kp,
                            const u16* __restrict__ VT2, const int* __restrict__ anchors,
                            u16* __restrict__ Out) {
  const int t = blockIdx.x;   // 0..255
  const int h = blockIdx.y;   // 0..15
  __shared__ int tiles[20];
  __shared__ __align__(16) float lg[16][292];    // logits; weights overlay per-row
  const int tid  = threadIdx.x;
  const int lane = tid & 63;
  const int wave = tid >> 6;
  const int g = lane >> 4;          // k-group 0..3
  const int c = lane & 15;

  if (tid < 16) tiles[tid] = anchors[(size_t)((h << 12) + (t * 16 + 15)) * 16 + tid];
  if (tid == 16) tiles[16] = t;            // local tile (order: anchors then local)
  if (tid >= 17 && tid < 20) tiles[tid] = 0;   // dummy tiles (results discarded)
  __syncthreads();

  // ---- QK: Q(16x128) . K_tile(16x128)^T; 5 fixed iters/wave, 1-ahead prefetch
  {
    const u16* qbase = Q + (size_t)(t * 16 + c) * 2048 + h * 128 + g * 8;
    bf16x8 qf[4];
#pragma unroll
    for (int ks = 0; ks < 4; ++ks) qf[ks] = *(const bf16x8*)(qbase + ks * 32);

    int tok_[5];
    const u16* kb_[5];
#pragma unroll
    for (int i = 0; i < 5; ++i) {
      int j = wave + 4 * i;                  // < 20
      tok_[i] = tiles[j] * 16 + c;
      kb_[i] = Kp + ((size_t)h * 4096 + tok_[i]) * 128 + g * 8;
    }
    bf16x8 kfp[2][4];
#pragma unroll
    for (int ks = 0; ks < 4; ++ks) kfp[0][ks] = *(const bf16x8*)(kb_[0] + ks * 32);
#pragma unroll
    for (int i = 0; i < 5; ++i) {
      if (i < 4) {
#pragma unroll
        for (int ks = 0; ks < 4; ++ks)
          kfp[(i + 1) & 1][ks] = *(const bf16x8*)(kb_[i + 1] + ks * 32);
      }
      f32x4 a = (f32x4){0.f, 0.f, 0.f, 0.f};
#pragma unroll
      for (int ks = 0; ks < 4; ++ks)
        a = __builtin_amdgcn_mfma_f32_16x16x32_bf16(qf[ks], kfp[i & 1][ks], a, 0, 0, 0);
      int j = wave + 4 * i;
      if (j < 17) {
#pragma unroll
        for (int r = 0; r < 4; ++r) {
          int qrow = g * 4 + r;
          float vv = a[r] * 0.088388347648318447f;   // 1/sqrt(128)
          if (tok_[i] > t * 16 + qrow) vv = -1e10f;  // future mask
          lg[qrow][j * 16 + c] = vv;
        }
      }
    }
  }
  __syncthreads();

  // ---- softmax per q row: row r handled by 16 threads (col = tid&15)
  {
    const int r = tid >> 4, cc = tid & 15;
    float vals[17];
    float mx = -3.0e38f;
#pragma unroll
    for (int i = 0; i < 17; ++i) { vals[i] = lg[r][i * 16 + cc]; mx = fmaxf(mx, vals[i]); }
#pragma unroll
    for (int d = 1; d < 16; d <<= 1) mx = fmaxf(mx, __shfl_xor(mx, d, 64));
    float sum = 0.f;
#pragma unroll
    for (int i = 0; i < 17; ++i) { vals[i] = __expf(vals[i] - mx); sum += vals[i]; }
#pragma unroll
    for (int d = 1; d < 16; d <<= 1) sum += __shfl_xor(sum, d, 64);
    float inv = sum > 0.f ? 1.0f / sum : 0.f;
    u16* wrow = (u16*)&lg[r][0];
#pragma unroll
    for (int i = 0; i < 17; ++i) wrow[i * 16 + cc] = f2bf(vals[i] * inv);
    wrow[272 + cc] = 0;                        // zero the pad tile's weights
  }
  __syncthreads();

  // ---- PV: out(16x288 . 288x128); wave owns 32 dims; 1-ahead B-pair prefetch
  {
    f32x4 o0 = (f32x4){0.f, 0.f, 0.f, 0.f}, o1 = o0;
    const int d0 = wave * 32;
    const size_t hb = (size_t)h * 256;
    const int keyin = (g & 1) * 8;
    const u16* wrow = (const u16*)&lg[c][0];
    const u16* vb_[9];
#pragma unroll
    for (int ks = 0; ks < 9; ++ks) vb_[ks] = VT2 + (hb + tiles[2 * ks + (g >> 1)]) * 2048;
    bf16x8 pb0[2], pb1[2];
    pb0[0] = *(const bf16x8*)(vb_[0] + (d0 + c) * 16 + keyin);
    pb1[0] = *(const bf16x8*)(vb_[0] + (d0 + 16 + c) * 16 + keyin);
#pragma unroll
    for (int ks = 0; ks < 9; ++ks) {
      if (ks < 8) {
        pb0[(ks + 1) & 1] = *(const bf16x8*)(vb_[ks + 1] + (d0 + c) * 16 + keyin);
        pb1[(ks + 1) & 1] = *(const bf16x8*)(vb_[ks + 1] + (d0 + 16 + c) * 16 + keyin);
      }
      bf16x8 af = *(const bf16x8*)(wrow + ks * 32 + g * 8);
      o0 = __builtin_amdgcn_mfma_f32_16x16x32_bf16(af, pb0[ks & 1], o0, 0, 0, 0);
      o1 = __builtin_amdgcn_mfma_f32_16x16x32_bf16(af, pb1[ks & 1], o1, 0, 0, 0);
    }
#pragma unroll
    for (int r = 0; r < 4; ++r) {
      int qrow = g * 4 + r;
      size_t base = (size_t)(t * 16 + qrow) * 2048 + h * 128;
      Out[base + d0 + c]      = f2bf(o0[r]);
      Out[base + d0 + 16 + c] = f2bf(o1[r]);
    }
  }
}

extern "C" void kernel_launch(void* const* d_in, const int* in_sizes, int n_in,
                              void* d_out, int out_size, void* d_ws, size_t ws_size,
                              hipStream_t stream) {
  (void)in_sizes; (void)n_in; (void)out_size; (void)ws_size;
  const float* x      = (const float*)d_in[0];
  const float* Wq     = (const float*)d_in[1];
  const float* Wk     = (const float*)d_in[2];
  const float* Wv     = (const float*)d_in[3];
  const float* Wo     = (const float*)d_in[4];
  const float* freqs  = (const float*)d_in[5];
  const int* anchors  = (const int*)d_in[6];
  float* out = (float*)d_out;

  char* ws = (char*)d_ws;
  const size_t MB = 1024 * 1024;
  // Layout (98 MB used):
  //  0..16  : xbf, later attnb (x dead after QKV GEMM)
  // 16..40  : wqkvT contiguous (live through QKV GEMM)
  // 40..48  : woT (live until final GEMM)
  // 48..64  : qbf (rotated, written by QKV epilogue)
  // 64..80  : Kp  (head-major rotated k, written by QKV epilogue)
  // 80..96  : VT2 (transposed v, written by QKV epilogue)
  // 96..98  : ct, st
  u16* xbf   = (u16*)(ws + 0);
  u16* wqkvT = (u16*)(ws + 16 * MB);   // (6144 x 2048) bf16, N x K
  u16* woT   = (u16*)(ws + 40 * MB);
  u16* qbf   = (u16*)(ws + 48 * MB);
  u16* Kp    = (u16*)(ws + 64 * MB);
  u16* VT2   = (u16*)(ws + 80 * MB);
  u16* attnb = (u16*)(ws + 0);
  float* ct  = (float*)(ws + 96 * MB);
  float* st  = (float*)(ws + 97 * MB);

  // prep1: weight transposes + x cast + trig table (one launch)
  prep1_kernel<<<25600, 256, 0, stream>>>(x, Wq, Wk, Wv, Wo, freqs,
                                          xbf, wqkvT, woT, ct, st);
  // fused QKV projection + rope/repack epilogue (prep2 eliminated)
  gemm128_kernel<2><<<dim3(48, 32), 256, 0, stream>>>(xbf, wqkvT, qbf, Kp, VT2,
                                                      ct, st, 4096, 6144, 2048);
  attn_kernel<<<dim3(256, 16), 256, 0, stream>>>(qbf, Kp, VT2, anchors, attnb);
  gemm128_kernel<0><<<dim3(16, 32), 256, 0, stream>>>(attnb, woT, out, nullptr, nullptr,
                                                      nullptr, nullptr, 4096, 2048, 2048);
}

// Round 11
// 225.746 us; speedup vs baseline: 1.1360x; 1.0200x over previous
//
#include <hip/hip_runtime.h>

typedef unsigned short u16;
typedef unsigned int u32;
typedef __attribute__((ext_vector_type(8))) short bf16x8;   // 8 bf16 in 4 VGPRs
typedef __attribute__((ext_vector_type(4))) float f32x4;

// ---------- bf16 helpers (RNE) ----------
__device__ __forceinline__ u16 f2bf(float f) {
  union { float f; u32 u; } v; v.f = f;
  u32 u = v.u;
  return (u16)((u + 0x7FFFu + ((u >> 16) & 1u)) >> 16);
}
__device__ __forceinline__ float bf2f(u16 s) {
  union { u32 u; float f; } v; v.u = ((u32)s) << 16;
  return v.f;
}

// ---------- async global->LDS (16B per lane) ----------
__device__ __forceinline__ void async16(const void* g, void* l) {
  __builtin_amdgcn_global_load_lds(
      (__attribute__((address_space(1))) void*)g,
      (__attribute__((address_space(3))) void*)l, 16, 0, 0);
}

// ---------- prep1: fused {4x weight transpose+cast, x cast, trig table} ----------
__global__ void prep1_kernel(const float* __restrict__ x,
                             const float* __restrict__ W0, const float* __restrict__ W1,
                             const float* __restrict__ W2, const float* __restrict__ W3,
                             const float* __restrict__ freqs,
                             u16* __restrict__ xbf, u16* __restrict__ wqkvT,
                             u16* __restrict__ woT,
                             float* __restrict__ ct, float* __restrict__ st) {
  __shared__ float tile[32][33];
  const int bid = blockIdx.x;
  const int tid = threadIdx.x;
  if (bid < 16384) {
    const int z = bid >> 12;
    const float* in = z == 0 ? W0 : z == 1 ? W1 : z == 2 ? W2 : W3;
    u16* out = z == 3 ? woT : wqkvT + (size_t)z * 4194304;
    const int local = bid & 4095;
    const int c0 = (local & 63) * 32, r0 = (local >> 6) * 32;
    const int tx = tid & 31, ty = tid >> 5;
#pragma unroll
    for (int i = ty; i < 32; i += 8) tile[i][tx] = in[(size_t)(r0 + i) * 2048 + c0 + tx];
    __syncthreads();
    const int cx = tid & 15, iy = tid >> 4;
#pragma unroll
    for (int i = iy; i < 32; i += 16) {
      u32 v = (u32)f2bf(tile[2 * cx][i]) | ((u32)f2bf(tile[2 * cx + 1][i]) << 16);
      *(u32*)(out + (size_t)(c0 + i) * 2048 + r0 + 2 * cx) = v;
    }
  } else if (bid < 24576) {
    int i = (bid - 16384) * 256 + tid;     // < 2097152
    float4 v = ((const float4*)x)[i];
    ushort4 o;
    o.x = f2bf(v.x); o.y = f2bf(v.y); o.z = f2bf(v.z); o.w = f2bf(v.w);
    ((ushort4*)xbf)[i] = o;
  } else {
    int i = (bid - 24576) * 256 + tid;     // < 262144
    float f = freqs[i];
    ct[i] = cosf(f); st[i] = sinf(f);
  }
}

// ---------- bf16 GEMM: C(MxN) = A(MxK) * Bt(NxK)^T, f32 accumulate ----------
// K-loop: proven 97us structure (128x128 tile, BK=64, 4 waves 2x2, single-buffer
// LDS, two __syncthreads per K-tile, zero bank conflicts).
// Fragment columns remapped so n and n+2 are 64 dims apart:
//   col(n) = (n&2)*32 + wc*32 + (n&1)*16 + c   -> RoPE pair (d, d+64) is
// thread-local (acc[m][n], acc[m][n+2]).
// MODE 0: plain f32 out (Wo). MODE 2: QKV-fused epilogue -- q/k rotated fully
// in-register (no LDS, no barriers); v transposed via padded LDS bounce.
template <int MODE>
__launch_bounds__(256, 2)
__global__ void gemm128_kernel(const u16* __restrict__ A, const u16* __restrict__ Bt,
                               void* __restrict__ C, u16* __restrict__ D1, u16* __restrict__ D2,
                               const float* __restrict__ ct, const float* __restrict__ st,
                               int M, int N, int K) {
  __shared__ __align__(16) char smem[33152];   // K-loop: As(16K)+Bs(16K); v-epilogue: f32[64][129]
  u16* As = (u16*)smem;
  u16* Bs = (u16*)(smem + 16384);
  const int tid  = threadIdx.x;
  const int lane = tid & 63;
  const int wave = tid >> 6;
  const int wr = wave >> 1, wc = wave & 1;
  const int g = lane >> 4, c = lane & 15;
  const int brow = blockIdx.y * 128;
  const int bcol = blockIdx.x * 128;

  int a_goff[4], b_goff[4], l_off[4];
#pragma unroll
  for (int i = 0; i < 4; ++i) {
    int p = (wave * 4 + i) * 1024 + lane * 16;        // linear byte in 16KB tile
    int row = p >> 7;                                 // 128B per row (64 bf16)
    int colb = (p & 127) ^ ((row & 7) << 4);          // inverse swizzle on source
    a_goff[i] = (brow + row) * K + (colb >> 1);
    b_goff[i] = (bcol + row) * K + (colb >> 1);
    l_off[i] = p;
  }

  f32x4 acc[4][4];
#pragma unroll
  for (int m = 0; m < 4; ++m)
#pragma unroll
    for (int n = 0; n < 4; ++n) acc[m][n] = (f32x4){0.f, 0.f, 0.f, 0.f};

  for (int k0 = 0; k0 < K; k0 += 64) {
#pragma unroll
    for (int i = 0; i < 4; ++i) {
      async16(A + a_goff[i] + k0, (char*)As + l_off[i]);
      async16(Bt + b_goff[i] + k0, (char*)Bs + l_off[i]);
    }
    __syncthreads();
#pragma unroll
    for (int kk = 0; kk < 2; ++kk) {
      bf16x8 af[4], bfr[4];
#pragma unroll
      for (int m = 0; m < 4; ++m) {
        int row = wr * 64 + m * 16 + c;
        int byte = (row << 7) + ((kk * 64 + (g << 4)) ^ ((row & 7) << 4));
        af[m] = *(const bf16x8*)((const char*)As + byte);
      }
#pragma unroll
      for (int n = 0; n < 4; ++n) {
        int row = ((n & 2) << 5) + wc * 32 + ((n & 1) << 4) + c;   // remapped col
        int byte = (row << 7) + ((kk * 64 + (g << 4)) ^ ((row & 7) << 4));
        bfr[n] = *(const bf16x8*)((const char*)Bs + byte);
      }
#pragma unroll
      for (int m = 0; m < 4; ++m)
#pragma unroll
        for (int n = 0; n < 4; ++n)
          acc[m][n] = __builtin_amdgcn_mfma_f32_16x16x32_bf16(af[m], bfr[n], acc[m][n], 0, 0, 0);
    }
    __syncthreads();
  }

  if (MODE == 2) {
    const int sel = bcol >> 11;                       // 0=q 1=k 2=v (block-uniform)
    const int hh  = (bcol & 2047) >> 7;               // head index
    if (sel < 2) {
      // ---- q/k: in-register RoPE; pair = (acc[m][n], acc[m][n+2]) ----
#pragma unroll
      for (int m = 0; m < 4; ++m)
#pragma unroll
        for (int r = 0; r < 4; ++r) {
          const int t = brow + wr * 64 + m * 16 + g * 4 + r;
          const int tb = t * 64;
#pragma unroll
          for (int n = 0; n < 2; ++n) {
            const int d = wc * 32 + (n << 4) + c;     // 0..63
            float cv = ct[tb + d], sv = st[tb + d];
            float a = acc[m][n][r], b = acc[m][n + 2][r];
            u16 lo = f2bf(a * cv - b * sv);
            u16 hi = f2bf(b * cv + a * sv);
            if (sel == 0) {
              u16* qd = (u16*)C + (size_t)t * 2048 + hh * 128 + d;
              qd[0] = lo; qd[64] = hi;
            } else {
              u16* kd = D1 + ((size_t)hh * 4096 + t) * 128 + d;
              kd[0] = lo; kd[64] = hi;
            }
          }
        }
    } else {
      // ---- v: transpose via padded LDS bounce -> VT2[h][tile][d][16] ----
      float* ep = (float*)smem;                       // [64][129]
#pragma unroll
      for (int half = 0; half < 2; ++half) {
        if (wr == half) {
#pragma unroll
          for (int m = 0; m < 4; ++m)
#pragma unroll
            for (int n = 0; n < 4; ++n)
#pragma unroll
              for (int r = 0; r < 4; ++r) {
                int lr = m * 16 + g * 4 + r;                          // 0..63
                int lc = ((n & 2) << 5) + wc * 32 + ((n & 1) << 4) + c;
                ep[lr * 129 + lc] = acc[m][n][r];
              }
        }
        __syncthreads();
        const int rowbase = brow + half * 64;
#pragma unroll
        for (int it = 0; it < 16; ++it) {
          int idx = it * 256 + tid;          // 0..4095
          int tl = idx >> 10;                // local tile 0..3
          int d  = (idx >> 3) & 127;
          int k2 = idx & 7;                  // u32 over 2 keys
          u32 lo = f2bf(ep[(tl * 16 + 2 * k2) * 129 + d]);
          u32 hi = f2bf(ep[(tl * 16 + 2 * k2 + 1) * 129 + d]);
          int tile = (rowbase >> 4) + tl;
          *(u32*)(D2 + (((size_t)(hh * 256 + tile) * 128 + d) * 16 + 2 * k2)) = lo | (hi << 16);
        }
        __syncthreads();
      }
    }
  } else {
    const int r0 = brow + wr * 64;
#pragma unroll
    for (int m = 0; m < 4; ++m)
#pragma unroll
      for (int n = 0; n < 4; ++n)
#pragma unroll
        for (int r = 0; r < 4; ++r) {
          int rr = r0 + m * 16 + g * 4 + r;
          int cc = bcol + ((n & 2) << 5) + wc * 32 + ((n & 1) << 4) + c;
          ((float*)C)[(size_t)rr * N + cc] = acc[m][n][r];
        }
  }
}

// ---------- sparse tile attention: one block per (tile t, head h) ----------
// 17 key tiles (16 anchors + local) padded to 20; 272 keys padded to 288 with
// zero weights. Q pre-rotated (S,2048). K from Kp [h][s][128]; V from VT2
// [h][tile][d][16]. bf16 softmax weights overlay the f32 logits buffer
// row-aligned (1168B rows: PV start-banks 2-way aliased = free). LDS 18.7KB.
__launch_bounds__(256, 6)
__global__ void attn_kernel(const u16* __restrict__ Q, const u16* __restrict__ Kp,
                            const u16* __restrict__ VT2, const int* __restrict__ anchors,
                            u16* __restrict__ Out) {
  const int t = blockIdx.x;   // 0..255
  const int h = blockIdx.y;   // 0..15
  __shared__ int tiles[20];
  __shared__ __align__(16) float lg[16][292];    // logits; weights overlay per-row
  const int tid  = threadIdx.x;
  const int lane = tid & 63;
  const int wave = tid >> 6;
  const int g = lane >> 4;          // k-group 0..3
  const int c = lane & 15;

  if (tid < 16) tiles[tid] = anchors[(size_t)((h << 12) + (t * 16 + 15)) * 16 + tid];
  if (tid == 16) tiles[16] = t;            // local tile (order: anchors then local)
  if (tid >= 17 && tid < 20) tiles[tid] = 0;   // dummy tiles (results discarded)
  __syncthreads();

  // ---- QK: Q(16x128) . K_tile(16x128)^T; 5 fixed iters/wave, 1-ahead prefetch
  {
    const u16* qbase = Q + (size_t)(t * 16 + c) * 2048 + h * 128 + g * 8;
    bf16x8 qf[4];
#pragma unroll
    for (int ks = 0; ks < 4; ++ks) qf[ks] = *(const bf16x8*)(qbase + ks * 32);

    int tok_[5];
    const u16* kb_[5];
#pragma unroll
    for (int i = 0; i < 5; ++i) {
      int j = wave + 4 * i;                  // < 20
      tok_[i] = tiles[j] * 16 + c;
      kb_[i] = Kp + ((size_t)h * 4096 + tok_[i]) * 128 + g * 8;
    }
    bf16x8 kfp[2][4];
#pragma unroll
    for (int ks = 0; ks < 4; ++ks) kfp[0][ks] = *(const bf16x8*)(kb_[0] + ks * 32);
#pragma unroll
    for (int i = 0; i < 5; ++i) {
      if (i < 4) {
#pragma unroll
        for (int ks = 0; ks < 4; ++ks)
          kfp[(i + 1) & 1][ks] = *(const bf16x8*)(kb_[i + 1] + ks * 32);
      }
      f32x4 a = (f32x4){0.f, 0.f, 0.f, 0.f};
#pragma unroll
      for (int ks = 0; ks < 4; ++ks)
        a = __builtin_amdgcn_mfma_f32_16x16x32_bf16(qf[ks], kfp[i & 1][ks], a, 0, 0, 0);
      int j = wave + 4 * i;
      if (j < 17) {
#pragma unroll
        for (int r = 0; r < 4; ++r) {
          int qrow = g * 4 + r;
          float vv = a[r] * 0.088388347648318447f;   // 1/sqrt(128)
          if (tok_[i] > t * 16 + qrow) vv = -1e10f;  // future mask
          lg[qrow][j * 16 + c] = vv;
        }
      }
    }
  }
  __syncthreads();

  // ---- softmax per q row: row r handled by 16 threads (col = tid&15)
  {
    const int r = tid >> 4, cc = tid & 15;
    float vals[17];
    float mx = -3.0e38f;
#pragma unroll
    for (int i = 0; i < 17; ++i) { vals[i] = lg[r][i * 16 + cc]; mx = fmaxf(mx, vals[i]); }
#pragma unroll
    for (int d = 1; d < 16; d <<= 1) mx = fmaxf(mx, __shfl_xor(mx, d, 64));
    float sum = 0.f;
#pragma unroll
    for (int i = 0; i < 17; ++i) { vals[i] = __expf(vals[i] - mx); sum += vals[i]; }
#pragma unroll
    for (int d = 1; d < 16; d <<= 1) sum += __shfl_xor(sum, d, 64);
    float inv = sum > 0.f ? 1.0f / sum : 0.f;
    u16* wrow = (u16*)&lg[r][0];
#pragma unroll
    for (int i = 0; i < 17; ++i) wrow[i * 16 + cc] = f2bf(vals[i] * inv);
    wrow[272 + cc] = 0;                        // zero the pad tile's weights
  }
  __syncthreads();

  // ---- PV: out(16x288 . 288x128); wave owns 32 dims; 1-ahead B-pair prefetch
  {
    f32x4 o0 = (f32x4){0.f, 0.f, 0.f, 0.f}, o1 = o0;
    const int d0 = wave * 32;
    const size_t hb = (size_t)h * 256;
    const int keyin = (g & 1) * 8;
    const u16* wrow = (const u16*)&lg[c][0];
    const u16* vb_[9];
#pragma unroll
    for (int ks = 0; ks < 9; ++ks) vb_[ks] = VT2 + (hb + tiles[2 * ks + (g >> 1)]) * 2048;
    bf16x8 pb0[2], pb1[2];
    pb0[0] = *(const bf16x8*)(vb_[0] + (d0 + c) * 16 + keyin);
    pb1[0] = *(const bf16x8*)(vb_[0] + (d0 + 16 + c) * 16 + keyin);
#pragma unroll
    for (int ks = 0; ks < 9; ++ks) {
      if (ks < 8) {
        pb0[(ks + 1) & 1] = *(const bf16x8*)(vb_[ks + 1] + (d0 + c) * 16 + keyin);
        pb1[(ks + 1) & 1] = *(const bf16x8*)(vb_[ks + 1] + (d0 + 16 + c) * 16 + keyin);
      }
      bf16x8 af = *(const bf16x8*)(wrow + ks * 32 + g * 8);
      o0 = __builtin_amdgcn_mfma_f32_16x16x32_bf16(af, pb0[ks & 1], o0, 0, 0, 0);
      o1 = __builtin_amdgcn_mfma_f32_16x16x32_bf16(af, pb1[ks & 1], o1, 0, 0, 0);
    }
#pragma unroll
    for (int r = 0; r < 4; ++r) {
      int qrow = g * 4 + r;
      size_t base = (size_t)(t * 16 + qrow) * 2048 + h * 128;
      Out[base + d0 + c]      = f2bf(o0[r]);
      Out[base + d0 + 16 + c] = f2bf(o1[r]);
    }
  }
}

extern "C" void kernel_launch(void* const* d_in, const int* in_sizes, int n_in,
                              void* d_out, int out_size, void* d_ws, size_t ws_size,
                              hipStream_t stream) {
  (void)in_sizes; (void)n_in; (void)out_size; (void)ws_size;
  const float* x      = (const float*)d_in[0];
  const float* Wq     = (const float*)d_in[1];
  const float* Wk     = (const float*)d_in[2];
  const float* Wv     = (const float*)d_in[3];
  const float* Wo     = (const float*)d_in[4];
  const float* freqs  = (const float*)d_in[5];
  const int* anchors  = (const int*)d_in[6];
  float* out = (float*)d_out;

  char* ws = (char*)d_ws;
  const size_t MB = 1024 * 1024;
  // Layout (98 MB used):
  //  0..16  : xbf, later attnb (x dead after QKV GEMM)
  // 16..40  : wqkvT contiguous (live through QKV GEMM)
  // 40..48  : woT (live until final GEMM)
  // 48..64  : qbf (rotated, written by QKV epilogue)
  // 64..80  : Kp  (head-major rotated k, written by QKV epilogue)
  // 80..96  : VT2 (transposed v, written by QKV epilogue)
  // 96..98  : ct, st
  u16* xbf   = (u16*)(ws + 0);
  u16* wqkvT = (u16*)(ws + 16 * MB);   // (6144 x 2048) bf16, N x K
  u16* woT   = (u16*)(ws + 40 * MB);
  u16* qbf   = (u16*)(ws + 48 * MB);
  u16* Kp    = (u16*)(ws + 64 * MB);
  u16* VT2   = (u16*)(ws + 80 * MB);
  u16* attnb = (u16*)(ws + 0);
  float* ct  = (float*)(ws + 96 * MB);
  float* st  = (float*)(ws + 97 * MB);

  // prep1: weight transposes + x cast + trig table (one launch)
  prep1_kernel<<<25600, 256, 0, stream>>>(x, Wq, Wk, Wv, Wo, freqs,
                                          xbf, wqkvT, woT, ct, st);
  // fused QKV projection + rope/repack epilogue
  gemm128_kernel<2><<<dim3(48, 32), 256, 0, stream>>>(xbf, wqkvT, qbf, Kp, VT2,
                                                      ct, st, 4096, 6144, 2048);
  attn_kernel<<<dim3(256, 16), 256, 0, stream>>>(qbf, Kp, VT2, anchors, attnb);
  gemm128_kernel<0><<<dim3(16, 32), 256, 0, stream>>>(attnb, woT, out, nullptr, nullptr,
                                                      nullptr, nullptr, 4096, 2048, 2048);
}